// Round 2
// baseline (1517.618 us; speedup 1.0000x reference)
//
#include <hip/hip_runtime.h>
#include <cmath>

// Problem constants
#define M 256
#define N 512
#define P 24
#define D 8

// ---------------------------------------------------------------------------
// self terms: s[i] = sum_{u,v} A[i,u]A[i,v] exp(-0.5*||x_u - x_v||^2)
// one wave per i; 576 pairs = 9 per lane
// ---------------------------------------------------------------------------
__global__ __launch_bounds__(64) void self_kernel(const float* __restrict__ X,
                                                  const float* __restrict__ A,
                                                  float* __restrict__ s) {
    const int i = blockIdx.x;
    const int lane = threadIdx.x;
    const float* Xi = X + (size_t)i * P * D;
    const float* Ai = A + (size_t)i * P;
    float acc = 0.f;
#pragma unroll
    for (int t = 0; t < 9; ++t) {
        int idx = lane + 64 * t;          // 0..575
        int u = idx / 24;
        int v = idx - u * 24;
        const float* xu = Xi + u * D;
        const float* xv = Xi + v * D;
        float d2 = 0.f;
#pragma unroll
        for (int d = 0; d < D; ++d) { float df = xu[d] - xv[d]; d2 = fmaf(df, df, d2); }
        acc = fmaf(Ai[u] * Ai[v], __expf(-0.5f * d2), acc);
    }
#pragma unroll
    for (int off = 1; off < 64; off <<= 1) acc += __shfl_xor(acc, off, 64);
    if (lane == 0) s[i] = acc;
}

// ---------------------------------------------------------------------------
// gram kernel: out[i][j] = nu * exp(-0.5*max(s1[i]+s2[j]-2*C_ij,0)/rho)
//   C_ij = sum_{u,v} A1[i,u] exp(-0.5||x1_u - x2_v||^2) A2[j,v]
// block: 128 threads = 16 i's x 8 u-chunks (3 u each). 16 j's staged in LDS.
// mode 0: nonsym f32 (Kox) | mode 1: sym f32 full (Kxx) | mode 2: sym lower f64 + nu*g diag (Koo)
// ---------------------------------------------------------------------------
__global__ __launch_bounds__(128) void gram_kernel(
    const float* __restrict__ X1, const float* __restrict__ A1, const float* __restrict__ s1,
    const float* __restrict__ X2, const float* __restrict__ A2, const float* __restrict__ s2,
    const float* __restrict__ rho_p, const float* __restrict__ nu_p, const float* __restrict__ g_p,
    float* __restrict__ outF, double* __restrict__ outD, int ldout, int mode) {
    const int it = blockIdx.x, jt = blockIdx.y;
    if (mode == 1 && jt < it) return;
    if (mode == 2 && jt > it) return;
    const int i0 = it * 16, j0 = jt * 16;
    const int tid = threadIdx.x;
    const int il = tid >> 3, uc = tid & 7;
    const int i = i0 + il;

    __shared__ __align__(16) float X2s[16 * 192];
    __shared__ float A2s[16 * 24];
    __shared__ float S2s[16];

    {
        const float4* gx = (const float4*)(X2 + (size_t)j0 * 192);
        float4* lx = (float4*)X2s;
        for (int idx = tid; idx < 16 * 48; idx += 128) lx[idx] = gx[idx];
        for (int idx = tid; idx < 16 * 24; idx += 128) A2s[idx] = A2[(size_t)j0 * 24 + idx];
        if (tid < 16) S2s[tid] = s2[j0 + tid];
    }
    __syncthreads();

    float x1r[3][8], a1r[3];
#pragma unroll
    for (int ss = 0; ss < 3; ++ss) {
        const float* p = X1 + ((size_t)i * P + uc * 3 + ss) * D;
#pragma unroll
        for (int d = 0; d < D; ++d) x1r[ss][d] = p[d];
        a1r[ss] = A1[(size_t)i * P + uc * 3 + ss];
    }
    const float s1i = s1[i];
    const float rho = rho_p[0], nu = nu_p[0], g = g_p[0];

    for (int jj = 0; jj < 16; ++jj) {
        float acc = 0.f;
        const float* xb = X2s + jj * 192;
#pragma unroll 4
        for (int v = 0; v < 24; ++v) {
            const float4 q0 = ((const float4*)(xb + v * 8))[0];
            const float4 q1 = ((const float4*)(xb + v * 8))[1];
            float x2r[8];
            x2r[0] = q0.x; x2r[1] = q0.y; x2r[2] = q0.z; x2r[3] = q0.w;
            x2r[4] = q1.x; x2r[5] = q1.y; x2r[6] = q1.z; x2r[7] = q1.w;
            float inner = 0.f;
#pragma unroll
            for (int ss = 0; ss < 3; ++ss) {
                float d2 = 0.f;
#pragma unroll
                for (int d = 0; d < D; ++d) { float df = x1r[ss][d] - x2r[d]; d2 = fmaf(df, df, d2); }
                inner = fmaf(a1r[ss], __expf(-0.5f * d2), inner);
            }
            acc = fmaf(A2s[jj * 24 + v], inner, acc);
        }
        acc += __shfl_xor(acc, 1, 8);
        acc += __shfl_xor(acc, 2, 8);
        acc += __shfl_xor(acc, 4, 8);
        if (uc == 0) {
            const int j = j0 + jj;
            float d2p = fmaxf(s1i + S2s[jj] - 2.f * acc, 0.f);
            float kv = __expf(-0.5f * d2p / rho);
            if (mode == 0) {
                outF[(size_t)i * ldout + j] = nu * kv;
            } else if (mode == 1) {
                float val = nu * kv;
                outF[(size_t)i * ldout + j] = val;
                if (jt != it) outF[(size_t)j * ldout + i] = val;  // diag tile covers itself
            } else {
                if (j <= i) outD[(size_t)i * ldout + j] = (double)(nu * (kv + ((i == j) ? g : 0.f)));
            }
        }
    }
}

// ---------------------------------------------------------------------------
// RHS setup: B (col-major [257][512] f64): cols 0..255 = Kox columns, col 256 = ones
// ---------------------------------------------------------------------------
__global__ __launch_bounds__(256) void rhs_kernel(const float* __restrict__ Kox,
                                                  double* __restrict__ B) {
    int idx = blockIdx.x * 256 + threadIdx.x;
    if (idx >= 257 * 512) return;
    int c = idx >> 9, n = idx & 511;
    B[idx] = (c < 256) ? (double)Kox[(size_t)n * 256 + c] : 1.0;
}

// ---------------------------------------------------------------------------
// Blocked Cholesky, panel = 64, f64, in-place on lower triangle of A [512x512]
// ---------------------------------------------------------------------------
__global__ __launch_bounds__(256) void potrf_kernel(double* __restrict__ A, int k0) {
    __shared__ double sA[64][65];
    const int tid = threadIdx.x;
    for (int idx = tid; idx < 4096; idx += 256) {
        int r = idx >> 6, c = idx & 63;
        sA[r][c] = A[(size_t)(k0 + r) * 512 + k0 + c];
    }
    __syncthreads();
    // deferred-scale Gaussian elimination (LDL-style): 1 barrier per step
    for (int k = 0; k < 63; ++k) {
        double inv = 1.0 / sA[k][k];
        for (int idx = tid; idx < 4096; idx += 256) {
            int r = idx >> 6, c = idx & 63;
            if (r > k && c > k && c <= r) sA[r][c] -= sA[r][k] * sA[c][k] * inv;
        }
        __syncthreads();
    }
    for (int idx = tid; idx < 4096; idx += 256) {
        int r = idx >> 6, c = idx & 63;
        if (c <= r) {
            double dq = sqrt(sA[c][c]);
            double v = (r == c) ? dq : sA[r][c] / dq;
            A[(size_t)(k0 + r) * 512 + k0 + c] = v;
        }
    }
}

// panel solve: L21 = A21 * L11^-T; one wave per row, L11 staged in LDS
__global__ __launch_bounds__(256) void trsm_kernel(double* __restrict__ A, int k0) {
    __shared__ double sL[64][65];
    const int tid = threadIdx.x;
    for (int idx = tid; idx < 4096; idx += 256) {
        int r = idx >> 6, c = idx & 63;
        sL[r][c] = A[(size_t)(k0 + r) * 512 + k0 + c];
    }
    __syncthreads();
    const int lane = tid & 63, w = tid >> 6;
    const int row = k0 + 64 + blockIdx.x * 4 + w;
    double a = A[(size_t)row * 512 + k0 + lane];
    double rd = 1.0 / sL[lane][lane];
    double x = 0.0;
    for (int j = 0; j < 64; ++j) {
        double term = (lane < j) ? sL[j][lane] * x : 0.0;
#pragma unroll
        for (int off = 1; off < 64; off <<= 1) term += __shfl_xor(term, off, 64);
        double nx = (a - term) * rd;
        if (lane == j) x = nx;
    }
    A[(size_t)row * 512 + k0 + lane] = x;
}

// trailing update: A[i][j] -= sum_t L[i][k0+t] L[j][k0+t], lower triangle only
__global__ __launch_bounds__(256) void syrk_kernel(double* __restrict__ A, int k0) {
    const int bi = blockIdx.y, bj = blockIdx.x;
    if (bj > bi) return;
    const int rs = k0 + 64;
    const int i0 = rs + bi * 32, j0 = rs + bj * 32;
    __shared__ double Li[32][65];
    __shared__ double Lj[32][65];
    const int tid = threadIdx.x;
    for (int idx = tid; idx < 2048; idx += 256) {
        int r = idx >> 6, c = idx & 63;
        Li[r][c] = A[(size_t)(i0 + r) * 512 + k0 + c];
        Lj[r][c] = A[(size_t)(j0 + r) * 512 + k0 + c];
    }
    __syncthreads();
    const int tx = tid & 15, ty = tid >> 4;
    double a00 = 0, a01 = 0, a10 = 0, a11 = 0;
#pragma unroll 8
    for (int t = 0; t < 64; ++t) {
        double u0 = Li[2 * ty][t], u1 = Li[2 * ty + 1][t];
        double v0 = Lj[2 * tx][t], v1 = Lj[2 * tx + 1][t];
        a00 = fma(u0, v0, a00); a01 = fma(u0, v1, a01);
        a10 = fma(u1, v0, a10); a11 = fma(u1, v1, a11);
    }
    const int ii = i0 + 2 * ty, jjc = j0 + 2 * tx;
    if (jjc     <= ii)     A[(size_t)ii * 512 + jjc]           -= a00;
    if (jjc + 1 <= ii)     A[(size_t)ii * 512 + jjc + 1]       -= a01;
    if (jjc     <= ii + 1) A[(size_t)(ii + 1) * 512 + jjc]     -= a10;
    if (jjc + 1 <= ii + 1) A[(size_t)(ii + 1) * 512 + jjc + 1] -= a11;
}

__global__ __launch_bounds__(256) void transpose_kernel(const double* __restrict__ L,
                                                        double* __restrict__ LT) {
    __shared__ double t[32][33];
    const int bx = blockIdx.x, by = blockIdx.y;
    const int tx = threadIdx.x & 31, ty = threadIdx.x >> 5;
#pragma unroll
    for (int p = 0; p < 4; ++p) {
        int r = by * 32 + ty + p * 8;
        t[ty + p * 8][tx] = L[(size_t)r * 512 + bx * 32 + tx];
    }
    __syncthreads();
#pragma unroll
    for (int p = 0; p < 4; ++p) {
        int r = bx * 32 + ty + p * 8;
        LT[(size_t)r * 512 + by * 32 + tx] = t[tx][ty + p * 8];
    }
}

// ---------------------------------------------------------------------------
// forward solve L y = b ; one wave per column; y register-resident (lane owns
// rows lane+64k); full-row dot recompute + butterfly reduce; row prefetch.
// ---------------------------------------------------------------------------
__global__ __launch_bounds__(64) void fwd_kernel(const double* __restrict__ L,
                                                 double* __restrict__ B) {
    const int c = blockIdx.x, lane = threadIdx.x;
    double* col = B + (size_t)c * 512;
    double b[8], y[8], rd[8], cur[8], nxt[8];
#pragma unroll
    for (int k = 0; k < 8; ++k) {
        int r = 64 * k + lane;
        b[k] = col[r];
        rd[k] = 1.0 / L[(size_t)r * 512 + r];
        y[k] = 0.0;
    }
#pragma unroll
    for (int kk = 0; kk < 8; ++kk) cur[kk] = L[(size_t)(64 * kk + lane)];  // row 0
#pragma unroll
    for (int k = 0; k < 8; ++k) {
        for (int li = 0; li < 64; li += 2) {
            {   // i = 64k+li : use cur, prefetch row i+1 -> nxt
                const int i = 64 * k + li;
                const int ip = (i + 1 < 512) ? i + 1 : 511;
                const double* rowp = L + (size_t)ip * 512 + lane;
#pragma unroll
                for (int kk = 0; kk < 8; ++kk) nxt[kk] = rowp[64 * kk];
                double acc = (lane < li) ? cur[k] * y[k] : 0.0;
#pragma unroll
                for (int kk = 0; kk < k; ++kk) acc = fma(cur[kk], y[kk], acc);
#pragma unroll
                for (int off = 1; off < 64; off <<= 1) acc += __shfl_xor(acc, off, 64);
                double ny = (b[k] - acc) * rd[k];
                if (lane == li) y[k] = ny;
            }
            {   // i = 64k+li+1 : use nxt, prefetch -> cur
                const int i = 64 * k + li + 1;
                const int ip = (i + 1 < 512) ? i + 1 : 511;
                const double* rowp = L + (size_t)ip * 512 + lane;
#pragma unroll
                for (int kk = 0; kk < 8; ++kk) cur[kk] = rowp[64 * kk];
                double acc = (lane < li + 1) ? nxt[k] * y[k] : 0.0;
#pragma unroll
                for (int kk = 0; kk < k; ++kk) acc = fma(nxt[kk], y[kk], acc);
#pragma unroll
                for (int off = 1; off < 64; off <<= 1) acc += __shfl_xor(acc, off, 64);
                double ny = (b[k] - acc) * rd[k];
                if (lane == li + 1) y[k] = ny;
            }
        }
    }
#pragma unroll
    for (int k = 0; k < 8; ++k) col[64 * k + lane] = y[k];
}

// backward solve L^T z = y using U = L^T (rows of LT are coalesced)
__global__ __launch_bounds__(64) void bwd_kernel(const double* __restrict__ U,
                                                 double* __restrict__ B) {
    const int c = blockIdx.x, lane = threadIdx.x;
    double* col = B + (size_t)c * 512;
    double b[8], z[8], rd[8], cur[8], nxt[8];
#pragma unroll
    for (int k = 0; k < 8; ++k) {
        int r = 64 * k + lane;
        b[k] = col[r];
        rd[k] = 1.0 / U[(size_t)r * 512 + r];
        z[k] = 0.0;
    }
#pragma unroll
    for (int kk = 0; kk < 8; ++kk) cur[kk] = U[(size_t)511 * 512 + 64 * kk + lane];
#pragma unroll
    for (int k = 7; k >= 0; --k) {
        for (int li = 63; li >= 0; li -= 2) {
            {   // i = 64k+li : use cur, prefetch row i-1 -> nxt
                const int i = 64 * k + li;
                const int ip = (i - 1 >= 0) ? i - 1 : 0;
                const double* rowp = U + (size_t)ip * 512 + lane;
#pragma unroll
                for (int kk = 0; kk < 8; ++kk) nxt[kk] = rowp[64 * kk];
                double acc = (lane > li) ? cur[k] * z[k] : 0.0;
#pragma unroll
                for (int kk = k + 1; kk < 8; ++kk) acc = fma(cur[kk], z[kk], acc);
#pragma unroll
                for (int off = 1; off < 64; off <<= 1) acc += __shfl_xor(acc, off, 64);
                double nz = (b[k] - acc) * rd[k];
                if (lane == li) z[k] = nz;
            }
            {   // i = 64k+li-1 : use nxt, prefetch -> cur
                const int i = 64 * k + li - 1;
                const int ip = (i - 1 >= 0) ? i - 1 : 0;
                const double* rowp = U + (size_t)ip * 512 + lane;
#pragma unroll
                for (int kk = 0; kk < 8; ++kk) cur[kk] = rowp[64 * kk];
                double acc = (lane > li - 1) ? nxt[k] * z[k] : 0.0;
#pragma unroll
                for (int kk = k + 1; kk < 8; ++kk) acc = fma(nxt[kk], z[kk], acc);
#pragma unroll
                for (int off = 1; off < 64; off <<= 1) acc += __shfl_xor(acc, off, 64);
                double nz = (b[k] - acc) * rd[k];
                if (lane == li - 1) z[k] = nz;
            }
        }
    }
#pragma unroll
    for (int k = 0; k < 8; ++k) col[64 * k + lane] = z[k];
}

// ---------------------------------------------------------------------------
// column reductions: mean[m] = b + sum_n Z[m][n]*(ys[n]-b); kbx[m] = sum_n Z[m][n];
// S = sum_n Z[256][n]  (Z stored col-major [257][512] in B)
// ---------------------------------------------------------------------------
__global__ __launch_bounds__(64) void colreduce_kernel(const double* __restrict__ Z,
                                                       const float* __restrict__ ys,
                                                       const float* __restrict__ b_p,
                                                       float* __restrict__ out,
                                                       double* __restrict__ kbx,
                                                       double* __restrict__ Sp) {
    const int c = blockIdx.x, lane = threadIdx.x;
    const double b = (double)b_p[0];
    double s0 = 0.0, s1 = 0.0;
#pragma unroll
    for (int t = 0; t < 8; ++t) {
        int n = lane + 64 * t;
        double zv = Z[(size_t)c * 512 + n];
        s0 += zv;
        s1 = fma(zv, (double)ys[n] - b, s1);
    }
#pragma unroll
    for (int off = 1; off < 64; off <<= 1) {
        s0 += __shfl_xor(s0, off, 64);
        s1 += __shfl_xor(s1, off, 64);
    }
    if (lane == 0) {
        if (c < 256) { out[c] = (float)(b + s1); kbx[c] = s0; }
        else Sp[0] = s0;
    }
}

// cov[i][j] = Kxx[i][j] - sum_n Z[i][n]*Kox[n][j] + (1-kbx[i])(1-kbx[j])/S
__global__ __launch_bounds__(256) void cov_kernel(const double* __restrict__ Z,
                                                  const float* __restrict__ Kox,
                                                  const float* __restrict__ Kxx,
                                                  const double* __restrict__ kbx,
                                                  const double* __restrict__ Sp,
                                                  float* __restrict__ out) {
    const int bj = blockIdx.x, bi = blockIdx.y;
    const int tx = threadIdx.x & 15, ty = threadIdx.x >> 4;
    const int i = bi * 16 + ty, j = bj * 16 + tx;
    __shared__ double sZ[16][17];
    __shared__ float sK[16][17];
    double acc = 0.0;
    for (int kt = 0; kt < 32; ++kt) {
        sZ[ty][tx] = Z[(size_t)i * 512 + kt * 16 + tx];
        sK[ty][tx] = Kox[(size_t)(kt * 16 + ty) * 256 + j];
        __syncthreads();
#pragma unroll
        for (int t = 0; t < 16; ++t) acc = fma(sZ[ty][t], (double)sK[t][tx], acc);
        __syncthreads();
    }
    const double S = Sp[0];
    const double corr = (1.0 - kbx[i]) * (1.0 - kbx[j]) / S;
    out[(size_t)(1 + i) * 256 + j] = (float)((double)Kxx[(size_t)i * 256 + j] - acc + corr);
}

// ---------------------------------------------------------------------------
extern "C" void kernel_launch(void* const* d_in, const int* in_sizes, int n_in,
                              void* d_out, int out_size, void* d_ws, size_t ws_size,
                              hipStream_t stream) {
    const float* X_test = (const float*)d_in[0];
    const float* A_test = (const float*)d_in[1];
    const float* X_obs  = (const float*)d_in[2];
    const float* A_obs  = (const float*)d_in[3];
    const float* ys     = (const float*)d_in[4];
    const float* rho_p  = (const float*)d_in[5];
    const float* g_p    = (const float*)d_in[6];
    const float* nu_p   = (const float*)d_in[7];
    const float* b_p    = (const float*)d_in[8];
    float* out = (float*)d_out;
    char* ws = (char*)d_ws;

    double* Koo = (double*)(ws + 0);         // 512*512*8 = 2097152
    double* LT  = (double*)(ws + 2097152);   // 2097152
    double* Bc  = (double*)(ws + 4194304);   // 257*512*8 = 1052672
    float*  Kox = (float*) (ws + 5246976);   // 512*256*4 = 524288
    float*  Kxx = (float*) (ws + 5771264);   // 256*256*4 = 262144
    float*  s1v = (float*) (ws + 6033408);   // 1024
    float*  s2v = (float*) (ws + 6034432);   // 2048
    double* kbx = (double*)(ws + 6036480);   // 2048
    double* Sp  = (double*)(ws + 6038528);   // 8

    self_kernel<<<M, 64, 0, stream>>>(X_test, A_test, s1v);
    self_kernel<<<N, 64, 0, stream>>>(X_obs,  A_obs,  s2v);

    // Kxx (sym), Kox (nonsym, [N][M]), Koo lower f64 (+nu*g diag)
    gram_kernel<<<dim3(16, 16), 128, 0, stream>>>(X_test, A_test, s1v, X_test, A_test, s1v,
                                                  rho_p, nu_p, g_p, Kxx, nullptr, 256, 1);
    gram_kernel<<<dim3(32, 16), 128, 0, stream>>>(X_obs, A_obs, s2v, X_test, A_test, s1v,
                                                  rho_p, nu_p, g_p, Kox, nullptr, 256, 0);
    gram_kernel<<<dim3(32, 32), 128, 0, stream>>>(X_obs, A_obs, s2v, X_obs, A_obs, s2v,
                                                  rho_p, nu_p, g_p, nullptr, Koo, 512, 2);

    rhs_kernel<<<514, 256, 0, stream>>>(Kox, Bc);

    for (int kb = 0; kb < 8; ++kb) {
        int k0 = kb * 64;
        potrf_kernel<<<1, 256, 0, stream>>>(Koo, k0);
        int rem = 512 - k0 - 64;
        if (rem > 0) {
            trsm_kernel<<<rem / 4, 256, 0, stream>>>(Koo, k0);
            syrk_kernel<<<dim3(rem / 32, rem / 32), 256, 0, stream>>>(Koo, k0);
        }
    }
    transpose_kernel<<<dim3(16, 16), 256, 0, stream>>>(Koo, LT);

    fwd_kernel<<<257, 64, 0, stream>>>(Koo, Bc);
    bwd_kernel<<<257, 64, 0, stream>>>(LT, Bc);

    colreduce_kernel<<<257, 64, 0, stream>>>(Bc, ys, b_p, out, kbx, Sp);
    cov_kernel<<<dim3(16, 16), 256, 0, stream>>>(Bc, Kox, Kxx, kbx, Sp, out);
}

// Round 3
// 1445.570 us; speedup vs baseline: 1.0498x; 1.0498x over previous
//
#include <hip/hip_runtime.h>
#include <cmath>

// Problem constants
#define M 256
#define N 512
#define P 24
#define D 8

// ---------------------------------------------------------------------------
// self terms: s[i] = sum_{u,v} A[i,u]A[i,v] exp(-0.5*||x_u - x_v||^2)
// one wave per i; 576 pairs = 9 per lane. Block M+N writes the ones-column of Bc.
// ---------------------------------------------------------------------------
__global__ __launch_bounds__(64) void self_kernel(const float* __restrict__ X_test,
                                                  const float* __restrict__ A_test,
                                                  const float* __restrict__ X_obs,
                                                  const float* __restrict__ A_obs,
                                                  float* __restrict__ s1,
                                                  float* __restrict__ s2,
                                                  double* __restrict__ Bc) {
    const int bid = blockIdx.x;
    const int lane = threadIdx.x;
    if (bid == M + N) {  // ones column (col 256 of Bc, col-major [257][512])
#pragma unroll
        for (int t = 0; t < 8; ++t) Bc[(size_t)256 * 512 + 64 * t + lane] = 1.0;
        return;
    }
    const float* X; const float* A; float* s; int i;
    if (bid < M) { X = X_test; A = A_test; s = s1; i = bid; }
    else         { X = X_obs;  A = A_obs;  s = s2; i = bid - M; }
    const float* Xi = X + (size_t)i * P * D;
    const float* Ai = A + (size_t)i * P;
    float acc = 0.f;
#pragma unroll
    for (int t = 0; t < 9; ++t) {
        int idx = lane + 64 * t;          // 0..575
        int u = idx / 24;
        int v = idx - u * 24;
        const float* xu = Xi + u * D;
        const float* xv = Xi + v * D;
        float d2 = 0.f;
#pragma unroll
        for (int d = 0; d < D; ++d) { float df = xu[d] - xv[d]; d2 = fmaf(df, df, d2); }
        acc = fmaf(Ai[u] * Ai[v], __expf(-0.5f * d2), acc);
    }
#pragma unroll
    for (int off = 1; off < 64; off <<= 1) acc += __shfl_xor(acc, off, 64);
    if (lane == 0) s[i] = acc;
}

// ---------------------------------------------------------------------------
// fused gram kernel, z selects mode:
//  z=0: Koo (obs,obs)  lower f64 + nu*g diag, it,jt<32, jt<=it
//  z=1: Kox (obs,test) f32 [N][M] AND Bc[test_col][obs_row] f64, it<32, jt<16
//  z=2: Kxx (test,test) f32 full sym, it,jt<16, jt>=it
// ---------------------------------------------------------------------------
__global__ __launch_bounds__(128) void gram_kernel(
    const float* __restrict__ Xt, const float* __restrict__ At, const float* __restrict__ s1,
    const float* __restrict__ Xo, const float* __restrict__ Ao, const float* __restrict__ s2,
    const float* __restrict__ rho_p, const float* __restrict__ nu_p, const float* __restrict__ g_p,
    float* __restrict__ Kox, float* __restrict__ Kxx, double* __restrict__ Koo,
    double* __restrict__ Bc) {
    const int mode = blockIdx.z;
    const int it = blockIdx.x, jt = blockIdx.y;
    const float *X1, *A1, *S1, *X2, *A2, *S2;
    if (mode == 0) {
        if (jt > it) return;
        X1 = Xo; A1 = Ao; S1 = s2; X2 = Xo; A2 = Ao; S2 = s2;
    } else if (mode == 1) {
        if (jt >= 16) return;
        X1 = Xo; A1 = Ao; S1 = s2; X2 = Xt; A2 = At; S2 = s1;
    } else {
        if (it >= 16 || jt >= 16 || jt < it) return;
        X1 = Xt; A1 = At; S1 = s1; X2 = Xt; A2 = At; S2 = s1;
    }
    const int i0 = it * 16, j0 = jt * 16;
    const int tid = threadIdx.x;
    const int il = tid >> 3, uc = tid & 7;
    const int i = i0 + il;

    __shared__ __align__(16) float X2s[16 * 192];
    __shared__ float A2s[16 * 24];
    __shared__ float S2s[16];
    {
        const float4* gx = (const float4*)(X2 + (size_t)j0 * 192);
        float4* lx = (float4*)X2s;
        for (int idx = tid; idx < 16 * 48; idx += 128) lx[idx] = gx[idx];
        for (int idx = tid; idx < 16 * 24; idx += 128) A2s[idx] = A2[(size_t)j0 * 24 + idx];
        if (tid < 16) S2s[tid] = S2[j0 + tid];
    }
    __syncthreads();

    float x1r[3][8], a1r[3];
#pragma unroll
    for (int ss = 0; ss < 3; ++ss) {
        const float* p = X1 + ((size_t)i * P + uc * 3 + ss) * D;
#pragma unroll
        for (int d = 0; d < D; ++d) x1r[ss][d] = p[d];
        a1r[ss] = A1[(size_t)i * P + uc * 3 + ss];
    }
    const float s1i = S1[i];
    const float rho = rho_p[0], nu = nu_p[0], g = g_p[0];

    for (int jj = 0; jj < 16; ++jj) {
        float acc = 0.f;
        const float* xb = X2s + jj * 192;
#pragma unroll 4
        for (int v = 0; v < 24; ++v) {
            const float4 q0 = ((const float4*)(xb + v * 8))[0];
            const float4 q1 = ((const float4*)(xb + v * 8))[1];
            float x2r[8];
            x2r[0] = q0.x; x2r[1] = q0.y; x2r[2] = q0.z; x2r[3] = q0.w;
            x2r[4] = q1.x; x2r[5] = q1.y; x2r[6] = q1.z; x2r[7] = q1.w;
            float inner = 0.f;
#pragma unroll
            for (int ss = 0; ss < 3; ++ss) {
                float d2 = 0.f;
#pragma unroll
                for (int d = 0; d < D; ++d) { float df = x1r[ss][d] - x2r[d]; d2 = fmaf(df, df, d2); }
                inner = fmaf(a1r[ss], __expf(-0.5f * d2), inner);
            }
            acc = fmaf(A2s[jj * 24 + v], inner, acc);
        }
        acc += __shfl_xor(acc, 1, 8);
        acc += __shfl_xor(acc, 2, 8);
        acc += __shfl_xor(acc, 4, 8);
        if (uc == 0) {
            const int j = j0 + jj;
            float d2p = fmaxf(s1i + S2s[jj] - 2.f * acc, 0.f);
            float kv = __expf(-0.5f * d2p / rho);
            if (mode == 1) {
                float val = nu * kv;
                Kox[(size_t)i * 256 + j] = val;
                Bc[(size_t)j * 512 + i] = (double)val;
            } else if (mode == 2) {
                float val = nu * kv;
                Kxx[(size_t)i * 256 + j] = val;
                if (jt != it) Kxx[(size_t)j * 256 + i] = val;
            } else {
                if (j <= i) Koo[(size_t)i * 512 + j] = (double)(nu * (kv + ((i == j) ? g : 0.f)));
            }
        }
    }
}

// ---------------------------------------------------------------------------
// potrf + triangular inverse of the 64x64 diagonal block.
// Elimination: LDL-style deferred scale (1 barrier/step). Then scale to L,
// then invert via 2x32 split (two parallel 32-column chains + 2 small GEMMs).
// Exports Dinv[kb] (= L_kk^-1, row-major) and DinvT[kb].
// ---------------------------------------------------------------------------
__global__ __launch_bounds__(256) void potrf_kernel(double* __restrict__ A,
                                                    double* __restrict__ Dinv,
                                                    double* __restrict__ DinvT,
                                                    int k0, int kb) {
    __shared__ double sA[64][65];
    __shared__ double sX[64][65];
    __shared__ double sT[32][33];
    __shared__ double sD[64];
    const int tid = threadIdx.x;
    for (int idx = tid; idx < 4096; idx += 256) {
        int r = idx >> 6, c = idx & 63;
        sA[r][c] = A[(size_t)(k0 + r) * 512 + k0 + c];
    }
    __syncthreads();
    for (int k = 0; k < 63; ++k) {
        double inv = 1.0 / sA[k][k];
        for (int idx = tid; idx < 4096; idx += 256) {
            int r = idx >> 6, c = idx & 63;
            if (r > k && c > k && c <= r) sA[r][c] -= sA[r][k] * sA[c][k] * inv;
        }
        __syncthreads();
    }
    if (tid < 64) sD[tid] = sqrt(sA[tid][tid]);
    __syncthreads();
    // scale to Cholesky factor in LDS + write back to global
    for (int idx = tid; idx < 4096; idx += 256) {
        int r = idx >> 6, c = idx & 63;
        if (c <= r) {
            double v = (r == c) ? sD[c] : sA[r][c] / sD[c];
            sA[r][c] = v;
            A[(size_t)(k0 + r) * 512 + k0 + c] = v;
        }
    }
    {   // zero sX
        double* f = &sX[0][0];
        for (int idx = tid; idx < 64 * 65; idx += 256) f[idx] = 0.0;
    }
    __syncthreads();
    // X11 = inv(L[0:32,0:32]) by thread-per-column; X22 = inv(L[32:,32:]) likewise
    if (tid < 64) {
        const int c = tid;
        const int rend = (c < 32) ? 32 : 64;
        sX[c][c] = 1.0 / sD[c];
        for (int r = c + 1; r < rend; ++r) {
            double acc = 0.0;
            for (int t = c; t < r; ++t) acc = fma(sA[r][t], sX[t][c], acc);
            sX[r][c] = -acc / sD[r];
        }
    }
    __syncthreads();
    // T = L21 * X11   (L21 = sA[32+a][t], t<32; X11 col b nonzero for t>=b)
    for (int idx = tid; idx < 1024; idx += 256) {
        int a = idx >> 5, b = idx & 31;
        double acc = 0.0;
        for (int t = b; t < 32; ++t) acc = fma(sA[32 + a][t], sX[t][b], acc);
        sT[a][b] = acc;
    }
    __syncthreads();
    // X21 = -X22 * T  (X22[a][t] nonzero for t<=a)
    for (int idx = tid; idx < 1024; idx += 256) {
        int a = idx >> 5, b = idx & 31;
        double acc = 0.0;
        for (int t = 0; t <= a; ++t) acc = fma(sX[32 + a][32 + t], sT[t][b], acc);
        sX[32 + a][b] = -acc;
    }
    __syncthreads();
    for (int idx = tid; idx < 4096; idx += 256) {
        int r = idx >> 6, c = idx & 63;
        double v = sX[r][c];
        Dinv[(size_t)kb * 4096 + idx] = v;
        DinvT[(size_t)kb * 4096 + c * 64 + r] = v;
    }
}

// ---------------------------------------------------------------------------
// panel solve as GEMM: L21 = A21 * Dinv^T  ([64x64] per block)
// ---------------------------------------------------------------------------
__global__ __launch_bounds__(256) void trsmg_kernel(double* __restrict__ A,
                                                    const double* __restrict__ DinvT,
                                                    int k0, int kb) {
    const int i0 = k0 + 64 + blockIdx.x * 64;
    __shared__ double sA[64][65];
    __shared__ double sB[64][65];
    const int tid = threadIdx.x;
    for (int idx = tid; idx < 4096; idx += 256) {
        int r = idx >> 6, c = idx & 63;
        sA[r][c] = A[(size_t)(i0 + r) * 512 + k0 + c];
        sB[r][c] = DinvT[(size_t)kb * 4096 + idx];
    }
    __syncthreads();
    const int tx = tid & 15, ty = tid >> 4;
    double acc[4][4] = {};
    for (int t = 0; t < 64; ++t) {
        double a0 = sA[4 * ty + 0][t], a1 = sA[4 * ty + 1][t];
        double a2 = sA[4 * ty + 2][t], a3 = sA[4 * ty + 3][t];
        double b0 = sB[t][4 * tx + 0], b1 = sB[t][4 * tx + 1];
        double b2 = sB[t][4 * tx + 2], b3 = sB[t][4 * tx + 3];
        acc[0][0] = fma(a0, b0, acc[0][0]); acc[0][1] = fma(a0, b1, acc[0][1]);
        acc[0][2] = fma(a0, b2, acc[0][2]); acc[0][3] = fma(a0, b3, acc[0][3]);
        acc[1][0] = fma(a1, b0, acc[1][0]); acc[1][1] = fma(a1, b1, acc[1][1]);
        acc[1][2] = fma(a1, b2, acc[1][2]); acc[1][3] = fma(a1, b3, acc[1][3]);
        acc[2][0] = fma(a2, b0, acc[2][0]); acc[2][1] = fma(a2, b1, acc[2][1]);
        acc[2][2] = fma(a2, b2, acc[2][2]); acc[2][3] = fma(a2, b3, acc[2][3]);
        acc[3][0] = fma(a3, b0, acc[3][0]); acc[3][1] = fma(a3, b1, acc[3][1]);
        acc[3][2] = fma(a3, b2, acc[3][2]); acc[3][3] = fma(a3, b3, acc[3][3]);
    }
#pragma unroll
    for (int r = 0; r < 4; ++r)
#pragma unroll
        for (int c = 0; c < 4; ++c)
            A[(size_t)(i0 + 4 * ty + r) * 512 + k0 + 4 * tx + c] = acc[r][c];
}

// trailing update: A[i][j] -= sum_t L[i][k0+t] L[j][k0+t], lower triangle only
__global__ __launch_bounds__(256) void syrk_kernel(double* __restrict__ A, int k0) {
    const int bi = blockIdx.y, bj = blockIdx.x;
    if (bj > bi) return;
    const int rs = k0 + 64;
    const int i0 = rs + bi * 32, j0 = rs + bj * 32;
    __shared__ double Li[32][65];
    __shared__ double Lj[32][65];
    const int tid = threadIdx.x;
    for (int idx = tid; idx < 2048; idx += 256) {
        int r = idx >> 6, c = idx & 63;
        Li[r][c] = A[(size_t)(i0 + r) * 512 + k0 + c];
        Lj[r][c] = A[(size_t)(j0 + r) * 512 + k0 + c];
    }
    __syncthreads();
    const int tx = tid & 15, ty = tid >> 4;
    double a00 = 0, a01 = 0, a10 = 0, a11 = 0;
#pragma unroll 8
    for (int t = 0; t < 64; ++t) {
        double u0 = Li[2 * ty][t], u1 = Li[2 * ty + 1][t];
        double v0 = Lj[2 * tx][t], v1 = Lj[2 * tx + 1][t];
        a00 = fma(u0, v0, a00); a01 = fma(u0, v1, a01);
        a10 = fma(u1, v0, a10); a11 = fma(u1, v1, a11);
    }
    const int ii = i0 + 2 * ty, jjc = j0 + 2 * tx;
    if (jjc     <= ii)     A[(size_t)ii * 512 + jjc]           -= a00;
    if (jjc + 1 <= ii)     A[(size_t)ii * 512 + jjc + 1]       -= a01;
    if (jjc     <= ii + 1) A[(size_t)(ii + 1) * 512 + jjc]     -= a10;
    if (jjc + 1 <= ii + 1) A[(size_t)(ii + 1) * 512 + jjc + 1] -= a11;
}

__global__ __launch_bounds__(256) void transpose_kernel(const double* __restrict__ L,
                                                        double* __restrict__ LT) {
    __shared__ double t[32][33];
    const int bx = blockIdx.x, by = blockIdx.y;
    const int tx = threadIdx.x & 31, ty = threadIdx.x >> 5;
#pragma unroll
    for (int p = 0; p < 4; ++p) {
        int r = by * 32 + ty + p * 8;
        t[ty + p * 8][tx] = L[(size_t)r * 512 + bx * 32 + tx];
    }
    __syncthreads();
#pragma unroll
    for (int p = 0; p < 4; ++p) {
        int r = bx * 32 + ty + p * 8;
        LT[(size_t)r * 512 + by * 32 + tx] = t[tx][ty + p * 8];
    }
}

// ---------------------------------------------------------------------------
// forward solve L y = b, one 64-lane block per column. Per panel k:
//   v[r] = b[64k+r] - sum_{j<64k} L[64k+r][j] * y[j]   (lane-private row stream)
//   y[64k+r] = sum_t Dinv_k[r][t] v[t] = sum_t DinvT[t*64+r] v[t]  (coalesced)
// ---------------------------------------------------------------------------
__global__ __launch_bounds__(64) void fwd_kernel(const double* __restrict__ L,
                                                 const double* __restrict__ DinvT,
                                                 double* __restrict__ B) {
    const int c = blockIdx.x, lane = threadIdx.x;
    double* col = B + (size_t)c * 512;
    __shared__ double y[512];
    __shared__ double v[64];
    double breg[8];
#pragma unroll
    for (int k = 0; k < 8; ++k) breg[k] = col[64 * k + lane];
    for (int k = 0; k < 8; ++k) {
        const double* row = L + (size_t)(64 * k + lane) * 512;
        double acc = 0.0;
        const int jmax = 64 * k;
        for (int j = 0; j < jmax; j += 8) {
            double2 l0 = *(const double2*)(row + j + 0);
            double2 l1 = *(const double2*)(row + j + 2);
            double2 l2 = *(const double2*)(row + j + 4);
            double2 l3 = *(const double2*)(row + j + 6);
            acc = fma(l0.x, y[j + 0], acc); acc = fma(l0.y, y[j + 1], acc);
            acc = fma(l1.x, y[j + 2], acc); acc = fma(l1.y, y[j + 3], acc);
            acc = fma(l2.x, y[j + 4], acc); acc = fma(l2.y, y[j + 5], acc);
            acc = fma(l3.x, y[j + 6], acc); acc = fma(l3.y, y[j + 7], acc);
        }
        v[lane] = breg[k] - acc;
        __syncthreads();
        const double* Dk = DinvT + (size_t)k * 4096;
        double yr = 0.0;
#pragma unroll 8
        for (int t = 0; t < 64; ++t) yr = fma(Dk[t * 64 + lane], v[t], yr);
        y[64 * k + lane] = yr;
        __syncthreads();
    }
#pragma unroll
    for (int k = 0; k < 8; ++k) col[64 * k + lane] = y[64 * k + lane];
}

// backward solve L^T z = y using U = L^T:
//   v[r] = y[64k+r] - sum_{j>=64(k+1)} U[64k+r][j] * z[j]
//   z[64k+r] = sum_t Dinv_k[t][r] v[t] = sum_t Dinv[t*64+r] v[t]   (coalesced)
__global__ __launch_bounds__(64) void bwd_kernel(const double* __restrict__ U,
                                                 const double* __restrict__ Dinv,
                                                 double* __restrict__ B) {
    const int c = blockIdx.x, lane = threadIdx.x;
    double* col = B + (size_t)c * 512;
    __shared__ double z[512];
    __shared__ double v[64];
    double breg[8];
#pragma unroll
    for (int k = 0; k < 8; ++k) breg[k] = col[64 * k + lane];
    for (int k = 7; k >= 0; --k) {
        const double* row = U + (size_t)(64 * k + lane) * 512;
        double acc = 0.0;
        for (int j = 64 * (k + 1); j < 512; j += 8) {
            double2 l0 = *(const double2*)(row + j + 0);
            double2 l1 = *(const double2*)(row + j + 2);
            double2 l2 = *(const double2*)(row + j + 4);
            double2 l3 = *(const double2*)(row + j + 6);
            acc = fma(l0.x, z[j + 0], acc); acc = fma(l0.y, z[j + 1], acc);
            acc = fma(l1.x, z[j + 2], acc); acc = fma(l1.y, z[j + 3], acc);
            acc = fma(l2.x, z[j + 4], acc); acc = fma(l2.y, z[j + 5], acc);
            acc = fma(l3.x, z[j + 6], acc); acc = fma(l3.y, z[j + 7], acc);
        }
        v[lane] = breg[k] - acc;
        __syncthreads();
        const double* Dk = Dinv + (size_t)k * 4096;
        double zr = 0.0;
#pragma unroll 8
        for (int t = 0; t < 64; ++t) zr = fma(Dk[t * 64 + lane], v[t], zr);
        z[64 * k + lane] = zr;
        __syncthreads();
    }
#pragma unroll
    for (int k = 0; k < 8; ++k) col[64 * k + lane] = z[64 * k + lane];
}

// ---------------------------------------------------------------------------
// column reductions over Z (col-major [257][512] in B)
// ---------------------------------------------------------------------------
__global__ __launch_bounds__(64) void colreduce_kernel(const double* __restrict__ Z,
                                                       const float* __restrict__ ys,
                                                       const float* __restrict__ b_p,
                                                       float* __restrict__ out,
                                                       double* __restrict__ kbx,
                                                       double* __restrict__ Sp) {
    const int c = blockIdx.x, lane = threadIdx.x;
    const double b = (double)b_p[0];
    double s0 = 0.0, s1 = 0.0;
#pragma unroll
    for (int t = 0; t < 8; ++t) {
        int n = lane + 64 * t;
        double zv = Z[(size_t)c * 512 + n];
        s0 += zv;
        s1 = fma(zv, (double)ys[n] - b, s1);
    }
#pragma unroll
    for (int off = 1; off < 64; off <<= 1) {
        s0 += __shfl_xor(s0, off, 64);
        s1 += __shfl_xor(s1, off, 64);
    }
    if (lane == 0) {
        if (c < 256) { out[c] = (float)(b + s1); kbx[c] = s0; }
        else Sp[0] = s0;
    }
}

// cov[i][j] = Kxx[i][j] - sum_n Z[i][n]*Kox[n][j] + (1-kbx[i])(1-kbx[j])/S
__global__ __launch_bounds__(256) void cov_kernel(const double* __restrict__ Z,
                                                  const float* __restrict__ Kox,
                                                  const float* __restrict__ Kxx,
                                                  const double* __restrict__ kbx,
                                                  const double* __restrict__ Sp,
                                                  float* __restrict__ out) {
    const int bj = blockIdx.x, bi = blockIdx.y;
    const int tx = threadIdx.x & 15, ty = threadIdx.x >> 4;
    const int i = bi * 16 + ty, j = bj * 16 + tx;
    __shared__ double sZ[16][17];
    __shared__ float sK[16][17];
    double acc = 0.0;
    for (int kt = 0; kt < 32; ++kt) {
        sZ[ty][tx] = Z[(size_t)i * 512 + kt * 16 + tx];
        sK[ty][tx] = Kox[(size_t)(kt * 16 + ty) * 256 + j];
        __syncthreads();
#pragma unroll
        for (int t = 0; t < 16; ++t) acc = fma(sZ[ty][t], (double)sK[t][tx], acc);
        __syncthreads();
    }
    const double S = Sp[0];
    const double corr = (1.0 - kbx[i]) * (1.0 - kbx[j]) / S;
    out[(size_t)(1 + i) * 256 + j] = (float)((double)Kxx[(size_t)i * 256 + j] - acc + corr);
}

// ---------------------------------------------------------------------------
extern "C" void kernel_launch(void* const* d_in, const int* in_sizes, int n_in,
                              void* d_out, int out_size, void* d_ws, size_t ws_size,
                              hipStream_t stream) {
    const float* X_test = (const float*)d_in[0];
    const float* A_test = (const float*)d_in[1];
    const float* X_obs  = (const float*)d_in[2];
    const float* A_obs  = (const float*)d_in[3];
    const float* ys     = (const float*)d_in[4];
    const float* rho_p  = (const float*)d_in[5];
    const float* g_p    = (const float*)d_in[6];
    const float* nu_p   = (const float*)d_in[7];
    const float* b_p    = (const float*)d_in[8];
    float* out = (float*)d_out;
    char* ws = (char*)d_ws;

    double* Koo  = (double*)(ws + 0);         // 2097152
    double* LT   = (double*)(ws + 2097152);   // 2097152
    double* Bc   = (double*)(ws + 4194304);   // 1052672
    float*  Kox  = (float*) (ws + 5246976);   // 524288
    float*  Kxx  = (float*) (ws + 5771264);   // 262144
    float*  s1v  = (float*) (ws + 6033408);   // 1024
    float*  s2v  = (float*) (ws + 6034432);   // 2048
    double* kbx  = (double*)(ws + 6036480);   // 2048
    double* Sp   = (double*)(ws + 6038528);   // 1024 (pad)
    double* Dinv = (double*)(ws + 6039552);   // 8*4096*8 = 262144
    double* DinvT= (double*)(ws + 6301696);   // 262144  (end 6563840)

    self_kernel<<<M + N + 1, 64, 0, stream>>>(X_test, A_test, X_obs, A_obs, s1v, s2v, Bc);

    gram_kernel<<<dim3(32, 32, 3), 128, 0, stream>>>(X_test, A_test, s1v,
                                                     X_obs, A_obs, s2v,
                                                     rho_p, nu_p, g_p,
                                                     Kox, Kxx, Koo, Bc);

    for (int kb = 0; kb < 8; ++kb) {
        int k0 = kb * 64;
        potrf_kernel<<<1, 256, 0, stream>>>(Koo, Dinv, DinvT, k0, kb);
        int rem = 512 - k0 - 64;
        if (rem > 0) {
            trsmg_kernel<<<rem / 64, 256, 0, stream>>>(Koo, DinvT, k0, kb);
            syrk_kernel<<<dim3(rem / 32, rem / 32), 256, 0, stream>>>(Koo, k0);
        }
    }
    transpose_kernel<<<dim3(16, 16), 256, 0, stream>>>(Koo, LT);

    fwd_kernel<<<257, 64, 0, stream>>>(Koo, DinvT, Bc);
    bwd_kernel<<<257, 64, 0, stream>>>(LT, Dinv, Bc);

    colreduce_kernel<<<257, 64, 0, stream>>>(Bc, ys, b_p, out, kbx, Sp);
    cov_kernel<<<dim3(16, 16), 256, 0, stream>>>(Bc, Kox, Kxx, kbx, Sp, out);
}

// Round 4
// 1012.360 us; speedup vs baseline: 1.4991x; 1.4279x over previous
//
#include <hip/hip_runtime.h>
#include <cmath>

// Problem constants
#define M 256
#define N 512
#define P 24
#define D 8

// ---------------------------------------------------------------------------
// self terms: s[i] = sum_{u,v} A[i,u]A[i,v] exp(-0.5*||x_u - x_v||^2)
// plus folded weights at[i,u] = A[i,u]*exp(-0.5*||x_iu||^2).
// Block M+N writes the ones-column of Bc.
// ---------------------------------------------------------------------------
__global__ __launch_bounds__(64) void self_kernel(const float* __restrict__ X_test,
                                                  const float* __restrict__ A_test,
                                                  const float* __restrict__ X_obs,
                                                  const float* __restrict__ A_obs,
                                                  float* __restrict__ s1,
                                                  float* __restrict__ s2,
                                                  float* __restrict__ atT,
                                                  float* __restrict__ atO,
                                                  double* __restrict__ Bc) {
    const int bid = blockIdx.x;
    const int lane = threadIdx.x;
    if (bid == M + N) {  // ones column (col 256 of Bc, col-major [257][512])
#pragma unroll
        for (int t = 0; t < 8; ++t) Bc[(size_t)256 * 512 + 64 * t + lane] = 1.0;
        return;
    }
    const float* X; const float* A; float* s; float* at; int i;
    if (bid < M) { X = X_test; A = A_test; s = s1; at = atT; i = bid; }
    else         { X = X_obs;  A = A_obs;  s = s2; at = atO; i = bid - M; }
    const float* Xi = X + (size_t)i * P * D;
    const float* Ai = A + (size_t)i * P;
    float acc = 0.f;
#pragma unroll
    for (int t = 0; t < 9; ++t) {
        int idx = lane + 64 * t;          // 0..575
        int u = idx / 24;
        int v = idx - u * 24;
        const float* xu = Xi + u * D;
        const float* xv = Xi + v * D;
        float d2 = 0.f;
#pragma unroll
        for (int d = 0; d < D; ++d) { float df = xu[d] - xv[d]; d2 = fmaf(df, df, d2); }
        acc = fmaf(Ai[u] * Ai[v], __expf(-0.5f * d2), acc);
    }
#pragma unroll
    for (int off = 1; off < 64; off <<= 1) acc += __shfl_xor(acc, off, 64);
    if (lane == 0) s[i] = acc;
    if (lane < 24) {
        const float* xp = Xi + lane * D;
        float q = 0.f;
#pragma unroll
        for (int d = 0; d < D; ++d) q = fmaf(xp[d], xp[d], q);
        at[(size_t)i * P + lane] = Ai[lane] * __expf(-0.5f * q);
    }
}

// ---------------------------------------------------------------------------
// fused gram kernel with norm-folded weights:
//   C_ij = sum_u at1[i,u] sum_v at2[j,v] exp(x1_iu . x2_jv)
//   out = nu * exp(-0.5*max(s1[i]+s2[j]-2*C_ij,0)/rho)
// tile: 16 i x 8 j, 128 threads = 16 il x 8 uc (3 u each).
// z=0: Koo lower f64 (+nu*g diag); z=1: Kox f32 [N][M] + Bc f64; z=2: Kxx sym
// ---------------------------------------------------------------------------
__global__ __launch_bounds__(128) void gram_kernel(
    const float* __restrict__ Xt, const float* __restrict__ atT, const float* __restrict__ s1,
    const float* __restrict__ Xo, const float* __restrict__ atO, const float* __restrict__ s2,
    const float* __restrict__ rho_p, const float* __restrict__ nu_p, const float* __restrict__ g_p,
    float* __restrict__ Kox, float* __restrict__ Kxx, double* __restrict__ Koo,
    double* __restrict__ Bc) {
    const int mode = blockIdx.z;
    const int it = blockIdx.x, jt = blockIdx.y;
    const float *X1, *AT1, *S1, *X2, *AT2, *S2;
    if (mode == 0) {
        if (jt > 2 * it + 1) return;
        X1 = Xo; AT1 = atO; S1 = s2; X2 = Xo; AT2 = atO; S2 = s2;
    } else if (mode == 1) {
        if (jt >= 32) return;
        X1 = Xo; AT1 = atO; S1 = s2; X2 = Xt; AT2 = atT; S2 = s1;
    } else {
        if (it >= 16 || jt >= 32 || jt < 2 * it) return;
        X1 = Xt; AT1 = atT; S1 = s1; X2 = Xt; AT2 = atT; S2 = s1;
    }
    const int i0 = it * 16, j0 = jt * 8;
    const int tid = threadIdx.x;
    const int il = tid >> 3, uc = tid & 7;
    const int i = i0 + il;

    __shared__ __align__(16) float X2s[8 * 192];
    __shared__ float A2s[8 * 24];
    __shared__ float S2s[8];
    {
        const float4* gx = (const float4*)(X2 + (size_t)j0 * 192);
        float4* lx = (float4*)X2s;
        for (int idx = tid; idx < 8 * 48; idx += 128) lx[idx] = gx[idx];
        for (int idx = tid; idx < 8 * 24; idx += 128) A2s[idx] = AT2[(size_t)j0 * 24 + idx];
        if (tid < 8) S2s[tid] = S2[j0 + tid];
    }
    __syncthreads();

    float x1r[3][8], at1r[3];
#pragma unroll
    for (int ss = 0; ss < 3; ++ss) {
        const float* p = X1 + ((size_t)i * P + uc * 3 + ss) * D;
#pragma unroll
        for (int d = 0; d < D; ++d) x1r[ss][d] = p[d];
        at1r[ss] = AT1[(size_t)i * P + uc * 3 + ss];
    }
    const float s1i = S1[i];
    const float rho = rho_p[0], nu = nu_p[0], g = g_p[0];

    for (int jj = 0; jj < 8; ++jj) {
        const float* xb = X2s + jj * 192;
        float e0 = 0.f, e1 = 0.f, e2 = 0.f;
#pragma unroll 4
        for (int v = 0; v < 24; ++v) {
            const float4 q0 = ((const float4*)(xb + v * 8))[0];
            const float4 q1 = ((const float4*)(xb + v * 8))[1];
            float x2r[8];
            x2r[0] = q0.x; x2r[1] = q0.y; x2r[2] = q0.z; x2r[3] = q0.w;
            x2r[4] = q1.x; x2r[5] = q1.y; x2r[6] = q1.z; x2r[7] = q1.w;
            const float w2 = A2s[jj * 24 + v];
            float d0 = 0.f, d1 = 0.f, d2 = 0.f;
#pragma unroll
            for (int dd = 0; dd < 8; ++dd) {
                d0 = fmaf(x1r[0][dd], x2r[dd], d0);
                d1 = fmaf(x1r[1][dd], x2r[dd], d1);
                d2 = fmaf(x1r[2][dd], x2r[dd], d2);
            }
            e0 = fmaf(w2, __expf(d0), e0);
            e1 = fmaf(w2, __expf(d1), e1);
            e2 = fmaf(w2, __expf(d2), e2);
        }
        float acc = at1r[0] * e0;
        acc = fmaf(at1r[1], e1, acc);
        acc = fmaf(at1r[2], e2, acc);
        acc += __shfl_xor(acc, 1, 8);
        acc += __shfl_xor(acc, 2, 8);
        acc += __shfl_xor(acc, 4, 8);
        if (uc == 0) {
            const int j = j0 + jj;
            float d2p = fmaxf(s1i + S2s[jj] - 2.f * acc, 0.f);
            float kv = __expf(-0.5f * d2p / rho);
            if (mode == 0) {
                if (j <= i) Koo[(size_t)i * 512 + j] = (double)(nu * (kv + ((i == j) ? g : 0.f)));
            } else if (mode == 1) {
                float val = nu * kv;
                Kox[(size_t)i * 256 + j] = val;
                Bc[(size_t)j * 512 + i] = (double)val;
            } else {
                float val = nu * kv;
                if (j >= i) {
                    Kxx[(size_t)i * 256 + j] = val;
                    if (j > i) Kxx[(size_t)j * 256 + i] = val;
                }
            }
        }
    }
}

// ---------------------------------------------------------------------------
// Whole blocked Cholesky (panel=64) in ONE dispatch. 120 blocks:
// per panel p: [factor(1)] [trsm(7-p)] [syrk((7-p)(8-p)/2)], synchronized by
// device-scope acquire/release counters (zeroed by memsetAsync each launch).
// factor: 16-wide internal panels; wave0 LDL + scale + 16x16 inverse;
// parallel interior trsm/syrk; 3-level assembly of Dinv = inv(L_pp) 64x64.
// Writes L (lower), LT (transpose), Dinv, DinvT.
// ---------------------------------------------------------------------------
#define NT_(p) (7 - (p))
#define NS_(p) ((7 - (p)) * (8 - (p)) / 2)

__device__ __forceinline__ void spin_ge(int* f, int target) {
    if (threadIdx.x == 0) {
        while (__hip_atomic_load(f, __ATOMIC_ACQUIRE, __HIP_MEMORY_SCOPE_AGENT) < target)
            __builtin_amdgcn_s_sleep(2);
    }
    __syncthreads();
}

__global__ __launch_bounds__(256) void chol_kernel(double* __restrict__ A,
                                                   double* __restrict__ LT,
                                                   double* __restrict__ Dinv,
                                                   double* __restrict__ DinvT,
                                                   int* __restrict__ flags) {
    int* fdone = flags;        // [8] factor done
    int* tdone = flags + 8;    // [8] trsm count
    int* s00   = flags + 16;   // [8] syrk tile (0,0) done
    int* scol0 = flags + 24;   // [8] syrk col-0 count
    int* sall  = flags + 32;   // [8] syrk total count

    int bid = blockIdx.x, p = 0, rem = bid;
    for (;; ++p) {
        int tot = 1 + NT_(p) + NS_(p);
        if (rem < tot) break;
        rem -= tot;
    }
    const int k0 = p * 64;
    const int tid = threadIdx.x;

    __shared__ double smem[2 * 64 * 65 + 3 * 16 * 17];   // 73 KB

    if (rem == 0) {
        // ---------------- factor block ----------------
        double (*sA)[65] = (double(*)[65])smem;
        double (*sX)[65] = (double(*)[65])(smem + 64 * 65);
        double* sW = smem + 2 * 64 * 65;                 // [3][16][17]
        if (p > 0) spin_ge(&s00[p - 1], 1);
        for (int idx = tid; idx < 4096; idx += 256) {
            int r = idx >> 6, c = idx & 63;
            sA[r][c] = (c <= r) ? A[(size_t)(k0 + r) * 512 + k0 + c] : 0.0;
            sX[r][c] = 0.0;
        }
        __syncthreads();
        for (int q = 0; q < 4; ++q) {
            const int b0 = 16 * q;
            if (tid < 64) {
                // LDL deferred-scale sweep, in-order same-wave LDS
                for (int k = 0; k < 15; ++k) {
                    double inv = 1.0 / sA[b0 + k][b0 + k];
#pragma unroll
                    for (int t = 0; t < 4; ++t) {
                        int idx = tid + 64 * t, r = idx >> 4, c = idx & 15;
                        if (r > k && c > k && c <= r)
                            sA[b0 + r][b0 + c] -= sA[b0 + r][b0 + k] * sA[b0 + c][b0 + k] * inv;
                    }
                    asm volatile("" ::: "memory");
                }
                // scale to true L: read diag first, broadcast via shfl
                double dq = (tid < 16) ? sqrt(sA[b0 + tid][b0 + tid]) : 1.0;
                asm volatile("" ::: "memory");
#pragma unroll
                for (int t = 0; t < 4; ++t) {
                    int idx = tid + 64 * t, r = idx >> 4, c = idx & 15;
                    double dcol = __shfl(dq, c, 64);
                    if (c <= r) sA[b0 + r][b0 + c] = (r == c) ? dcol : sA[b0 + r][b0 + c] / dcol;
                }
                asm volatile("" ::: "memory");
                // X_qq = inv(L_qq): 4 lanes per column
                int c = tid >> 2, qd = tid & 3;
                if (qd == 0) sX[b0 + c][b0 + c] = 1.0 / sA[b0 + c][b0 + c];
                asm volatile("" ::: "memory");
                for (int r = 1; r < 16; ++r) {
                    double partial = 0.0;
                    for (int t = c + qd; t < r; t += 4)
                        partial = fma(sA[b0 + r][b0 + t], sX[b0 + t][b0 + c], partial);
                    partial += __shfl_xor(partial, 1, 4);
                    partial += __shfl_xor(partial, 2, 4);
                    if (qd == 0 && r > c)
                        sX[b0 + r][b0 + c] = -partial / sA[b0 + r][b0 + r];
                    asm volatile("" ::: "memory");
                }
            }
            __syncthreads();
            if (q < 3) {
                const int nrows = 48 - b0;
                const int cells = nrows * 16;
                double tv[3];
#pragma unroll
                for (int ii = 0; ii < 3; ++ii) {
                    int idx = tid + 256 * ii;
                    tv[ii] = 0.0;
                    if (idx < cells) {
                        int a = b0 + 16 + (idx >> 4), cc = idx & 15;
                        double acc = 0.0;
                        for (int t = 0; t <= cc; ++t)
                            acc = fma(sA[a][b0 + t], sX[b0 + cc][b0 + t], acc);
                        tv[ii] = acc;
                    }
                }
                __syncthreads();
#pragma unroll
                for (int ii = 0; ii < 3; ++ii) {
                    int idx = tid + 256 * ii;
                    if (idx < cells) {
                        int a = b0 + 16 + (idx >> 4), cc = idx & 15;
                        sA[a][b0 + cc] = tv[ii];
                    }
                }
                __syncthreads();
                for (int idx = tid; idx < nrows * nrows; idx += 256) {
                    int r = b0 + 16 + idx / nrows, cc = b0 + 16 + idx % nrows;
                    if (cc <= r) {
                        double acc = 0.0;
#pragma unroll
                        for (int t = 0; t < 16; ++t)
                            acc = fma(sA[r][b0 + t], sA[cc][b0 + t], acc);
                        sA[r][cc] -= acc;
                    }
                }
                __syncthreads();
            }
        }
        // assemble off-diagonal 16x16 blocks of X = inv(L64): 3 levels
        for (int d = 1; d <= 3; ++d) {
            __syncthreads();
            int npairs = 4 - d;
            for (int i2 = tid; i2 < npairs * 256; i2 += 256) {
                int pr = i2 >> 8, cell = i2 & 255, r = cell >> 4, c = cell & 15;
                int qc = pr, qr = pr + d;
                double w = 0.0;
                for (int t = 16 * qc; t < 16 * qr; ++t)
                    w = fma(sA[16 * qr + r][t], sX[t][16 * qc + c], w);
                sW[pr * 272 + r * 17 + c] = w;
            }
            __syncthreads();
            for (int i2 = tid; i2 < npairs * 256; i2 += 256) {
                int pr = i2 >> 8, cell = i2 & 255, r = cell >> 4, c = cell & 15;
                int qc = pr, qr = pr + d;
                double x = 0.0;
                for (int t = 0; t <= r; ++t)
                    x = fma(sX[16 * qr + r][16 * qr + t], sW[pr * 272 + t * 17 + c], x);
                sX[16 * qr + r][16 * qc + c] = -x;
            }
        }
        __syncthreads();
        for (int idx = tid; idx < 4096; idx += 256) {
            int r = idx >> 6, c = idx & 63;
            if (c <= r) {
                double lv = sA[r][c];
                A[(size_t)(k0 + r) * 512 + k0 + c] = lv;
                LT[(size_t)(k0 + c) * 512 + k0 + r] = lv;
            }
            double xv = sX[r][c];
            Dinv[(size_t)p * 4096 + idx] = xv;
            DinvT[(size_t)p * 4096 + (size_t)c * 64 + r] = xv;
        }
        __syncthreads();
        if (tid == 0) __hip_atomic_fetch_add(&fdone[p], 1, __ATOMIC_RELEASE, __HIP_MEMORY_SCOPE_AGENT);

    } else if (rem <= NT_(p)) {
        // ---------------- trsm block: L21 = A21 * Dinv^T ----------------
        double (*sA)[65] = (double(*)[65])smem;
        double (*sB)[65] = (double(*)[65])(smem + 64 * 65);
        const int b = rem - 1;
        const int i0 = k0 + 64 + b * 64;
        if (p > 0) spin_ge(&scol0[p - 1], NT_(p - 1));
        spin_ge(&fdone[p], 1);
        for (int idx = tid; idx < 4096; idx += 256) {
            int r = idx >> 6, c = idx & 63;
            sA[r][c] = A[(size_t)(i0 + r) * 512 + k0 + c];
            sB[r][c] = DinvT[(size_t)p * 4096 + idx];
        }
        __syncthreads();
        const int tx = tid & 15, ty = tid >> 4;
        double acc[4][4] = {};
        for (int t = 0; t < 64; ++t) {
            double a0 = sA[4 * ty + 0][t], a1 = sA[4 * ty + 1][t];
            double a2 = sA[4 * ty + 2][t], a3 = sA[4 * ty + 3][t];
            double b0 = sB[t][4 * tx + 0], b1 = sB[t][4 * tx + 1];
            double b2 = sB[t][4 * tx + 2], b3 = sB[t][4 * tx + 3];
            acc[0][0] = fma(a0, b0, acc[0][0]); acc[0][1] = fma(a0, b1, acc[0][1]);
            acc[0][2] = fma(a0, b2, acc[0][2]); acc[0][3] = fma(a0, b3, acc[0][3]);
            acc[1][0] = fma(a1, b0, acc[1][0]); acc[1][1] = fma(a1, b1, acc[1][1]);
            acc[1][2] = fma(a1, b2, acc[1][2]); acc[1][3] = fma(a1, b3, acc[1][3]);
            acc[2][0] = fma(a2, b0, acc[2][0]); acc[2][1] = fma(a2, b1, acc[2][1]);
            acc[2][2] = fma(a2, b2, acc[2][2]); acc[2][3] = fma(a2, b3, acc[2][3]);
            acc[3][0] = fma(a3, b0, acc[3][0]); acc[3][1] = fma(a3, b1, acc[3][1]);
            acc[3][2] = fma(a3, b2, acc[3][2]); acc[3][3] = fma(a3, b3, acc[3][3]);
        }
#pragma unroll
        for (int r = 0; r < 4; ++r)
#pragma unroll
            for (int c = 0; c < 4; ++c) {
                A[(size_t)(i0 + 4 * ty + r) * 512 + k0 + 4 * tx + c] = acc[r][c];
                LT[(size_t)(k0 + 4 * tx + c) * 512 + i0 + 4 * ty + r] = acc[r][c];
            }
        __syncthreads();
        if (tid == 0) __hip_atomic_fetch_add(&tdone[p], 1, __ATOMIC_RELEASE, __HIP_MEMORY_SCOPE_AGENT);

    } else {
        // ---------------- syrk block: A[i0,j0] -= Li * Lj^T ----------------
        double (*Li)[65] = (double(*)[65])smem;
        double (*Lj)[65] = (double(*)[65])(smem + 64 * 65);
        int s = rem - 1 - NT_(p);
        int bi = 0;
        while (s >= (bi + 1) * (bi + 2) / 2) ++bi;
        int bj = s - bi * (bi + 1) / 2;
        const int i0 = k0 + 64 + bi * 64, j0 = k0 + 64 + bj * 64;
        if (p > 0) spin_ge(&sall[p - 1], NS_(p - 1));
        spin_ge(&tdone[p], NT_(p));
        for (int idx = tid; idx < 4096; idx += 256) {
            int r = idx >> 6, c = idx & 63;
            Li[r][c] = A[(size_t)(i0 + r) * 512 + k0 + c];
            Lj[r][c] = A[(size_t)(j0 + r) * 512 + k0 + c];
        }
        __syncthreads();
        const int tx = tid & 15, ty = tid >> 4;
        double acc[4][4] = {};
        for (int t = 0; t < 64; ++t) {
            double a0 = Li[4 * ty + 0][t], a1 = Li[4 * ty + 1][t];
            double a2 = Li[4 * ty + 2][t], a3 = Li[4 * ty + 3][t];
            double b0 = Lj[4 * tx + 0][t], b1 = Lj[4 * tx + 1][t];
            double b2 = Lj[4 * tx + 2][t], b3 = Lj[4 * tx + 3][t];
            acc[0][0] = fma(a0, b0, acc[0][0]); acc[0][1] = fma(a0, b1, acc[0][1]);
            acc[0][2] = fma(a0, b2, acc[0][2]); acc[0][3] = fma(a0, b3, acc[0][3]);
            acc[1][0] = fma(a1, b0, acc[1][0]); acc[1][1] = fma(a1, b1, acc[1][1]);
            acc[1][2] = fma(a1, b2, acc[1][2]); acc[1][3] = fma(a1, b3, acc[1][3]);
            acc[2][0] = fma(a2, b0, acc[2][0]); acc[2][1] = fma(a2, b1, acc[2][1]);
            acc[2][2] = fma(a2, b2, acc[2][2]); acc[2][3] = fma(a2, b3, acc[2][3]);
            acc[3][0] = fma(a3, b0, acc[3][0]); acc[3][1] = fma(a3, b1, acc[3][1]);
            acc[3][2] = fma(a3, b2, acc[3][2]); acc[3][3] = fma(a3, b3, acc[3][3]);
        }
#pragma unroll
        for (int r = 0; r < 4; ++r)
#pragma unroll
            for (int c = 0; c < 4; ++c) {
                int gi = i0 + 4 * ty + r, gj = j0 + 4 * tx + c;
                if (bi != bj || gj <= gi) A[(size_t)gi * 512 + gj] -= acc[r][c];
            }
        __syncthreads();
        if (tid == 0) {
            __hip_atomic_fetch_add(&sall[p], 1, __ATOMIC_RELEASE, __HIP_MEMORY_SCOPE_AGENT);
            if (bj == 0) __hip_atomic_fetch_add(&scol0[p], 1, __ATOMIC_RELEASE, __HIP_MEMORY_SCOPE_AGENT);
            if (bi == 0 && bj == 0) __hip_atomic_fetch_add(&s00[p], 1, __ATOMIC_RELEASE, __HIP_MEMORY_SCOPE_AGENT);
        }
    }
}

// ---------------------------------------------------------------------------
// fused solve per column: L y = b (fwd), L^T z = y (bwd), then column
// reductions: mean/kbx/S. One 64-lane block per RHS column.
// ---------------------------------------------------------------------------
__global__ __launch_bounds__(64) void solve_kernel(const double* __restrict__ L,
                                                   const double* __restrict__ U,
                                                   const double* __restrict__ Dinv,
                                                   const double* __restrict__ DinvT,
                                                   double* __restrict__ B,
                                                   const float* __restrict__ ys,
                                                   const float* __restrict__ b_p,
                                                   float* __restrict__ out,
                                                   double* __restrict__ kbx,
                                                   double* __restrict__ Sp) {
    const int c = blockIdx.x, lane = threadIdx.x;
    double* col = B + (size_t)c * 512;
    __shared__ double y[512];
    __shared__ double z[512];
    __shared__ double v[64];
    double breg[8];
#pragma unroll
    for (int k = 0; k < 8; ++k) breg[k] = col[64 * k + lane];
    // forward: per panel, v = b - L21*y_prev ; y_panel = Dinv * v
    for (int k = 0; k < 8; ++k) {
        const double* row = L + (size_t)(64 * k + lane) * 512;
        double acc = 0.0;
        for (int j = 0; j < 64 * k; j += 8) {
            double2 l0 = *(const double2*)(row + j + 0);
            double2 l1 = *(const double2*)(row + j + 2);
            double2 l2 = *(const double2*)(row + j + 4);
            double2 l3 = *(const double2*)(row + j + 6);
            acc = fma(l0.x, y[j + 0], acc); acc = fma(l0.y, y[j + 1], acc);
            acc = fma(l1.x, y[j + 2], acc); acc = fma(l1.y, y[j + 3], acc);
            acc = fma(l2.x, y[j + 4], acc); acc = fma(l2.y, y[j + 5], acc);
            acc = fma(l3.x, y[j + 6], acc); acc = fma(l3.y, y[j + 7], acc);
        }
        v[lane] = breg[k] - acc;
        __syncthreads();
        const double* Dk = DinvT + (size_t)k * 4096;
        double yr = 0.0;
#pragma unroll 8
        for (int t = 0; t < 64; ++t) yr = fma(Dk[t * 64 + lane], v[t], yr);
        y[64 * k + lane] = yr;
        __syncthreads();
    }
    // backward with U = L^T
    for (int k = 7; k >= 0; --k) {
        const double* row = U + (size_t)(64 * k + lane) * 512;
        double acc = 0.0;
        for (int j = 64 * (k + 1); j < 512; j += 8) {
            double2 l0 = *(const double2*)(row + j + 0);
            double2 l1 = *(const double2*)(row + j + 2);
            double2 l2 = *(const double2*)(row + j + 4);
            double2 l3 = *(const double2*)(row + j + 6);
            acc = fma(l0.x, z[j + 0], acc); acc = fma(l0.y, z[j + 1], acc);
            acc = fma(l1.x, z[j + 2], acc); acc = fma(l1.y, z[j + 3], acc);
            acc = fma(l2.x, z[j + 4], acc); acc = fma(l2.y, z[j + 5], acc);
            acc = fma(l3.x, z[j + 6], acc); acc = fma(l3.y, z[j + 7], acc);
        }
        v[lane] = y[64 * k + lane] - acc;
        __syncthreads();
        const double* Dk = Dinv + (size_t)k * 4096;
        double zr = 0.0;
#pragma unroll 8
        for (int t = 0; t < 64; ++t) zr = fma(Dk[t * 64 + lane], v[t], zr);
        z[64 * k + lane] = zr;
        __syncthreads();
    }
    // write back + column reductions
    const double b = (double)b_p[0];
    double s0 = 0.0, s1 = 0.0;
#pragma unroll
    for (int k = 0; k < 8; ++k) {
        int n = 64 * k + lane;
        double zv = z[n];
        col[n] = zv;
        s0 += zv;
        s1 = fma(zv, (double)ys[n] - b, s1);
    }
#pragma unroll
    for (int off = 1; off < 64; off <<= 1) {
        s0 += __shfl_xor(s0, off, 64);
        s1 += __shfl_xor(s1, off, 64);
    }
    if (lane == 0) {
        if (c < 256) { out[c] = (float)(b + s1); kbx[c] = s0; }
        else Sp[0] = s0;
    }
}

// cov[i][j] = Kxx[i][j] - sum_n Z[i][n]*Kox[n][j] + (1-kbx[i])(1-kbx[j])/S
__global__ __launch_bounds__(256) void cov_kernel(const double* __restrict__ Z,
                                                  const float* __restrict__ Kox,
                                                  const float* __restrict__ Kxx,
                                                  const double* __restrict__ kbx,
                                                  const double* __restrict__ Sp,
                                                  float* __restrict__ out) {
    const int bj = blockIdx.x, bi = blockIdx.y;
    const int tx = threadIdx.x & 15, ty = threadIdx.x >> 4;
    const int i = bi * 16 + ty, j = bj * 16 + tx;
    __shared__ double sZ[16][17];
    __shared__ float sK[16][17];
    double acc = 0.0;
    for (int kt = 0; kt < 32; ++kt) {
        sZ[ty][tx] = Z[(size_t)i * 512 + kt * 16 + tx];
        sK[ty][tx] = Kox[(size_t)(kt * 16 + ty) * 256 + j];
        __syncthreads();
#pragma unroll
        for (int t = 0; t < 16; ++t) acc = fma(sZ[ty][t], (double)sK[t][tx], acc);
        __syncthreads();
    }
    const double S = Sp[0];
    const double corr = (1.0 - kbx[i]) * (1.0 - kbx[j]) / S;
    out[(size_t)(1 + i) * 256 + j] = (float)((double)Kxx[(size_t)i * 256 + j] - acc + corr);
}

// ---------------------------------------------------------------------------
extern "C" void kernel_launch(void* const* d_in, const int* in_sizes, int n_in,
                              void* d_out, int out_size, void* d_ws, size_t ws_size,
                              hipStream_t stream) {
    const float* X_test = (const float*)d_in[0];
    const float* A_test = (const float*)d_in[1];
    const float* X_obs  = (const float*)d_in[2];
    const float* A_obs  = (const float*)d_in[3];
    const float* ys     = (const float*)d_in[4];
    const float* rho_p  = (const float*)d_in[5];
    const float* g_p    = (const float*)d_in[6];
    const float* nu_p   = (const float*)d_in[7];
    const float* b_p    = (const float*)d_in[8];
    float* out = (float*)d_out;
    char* ws = (char*)d_ws;

    double* Koo  = (double*)(ws + 0);         // 2,097,152
    double* LT   = (double*)(ws + 2097152);   // 2,097,152
    double* Bc   = (double*)(ws + 4194304);   // 1,052,672
    float*  Kox  = (float*) (ws + 5246976);   // 524,288
    float*  Kxx  = (float*) (ws + 5771264);   // 262,144
    float*  s1v  = (float*) (ws + 6033408);   // 1,024
    float*  s2v  = (float*) (ws + 6034432);   // 2,048
    double* kbx  = (double*)(ws + 6036480);   // 2,048
    double* Sp   = (double*)(ws + 6038528);   // 8 (+pad)
    int*    flags= (int*)   (ws + 6038784);   // 160 B (inside Sp pad)
    double* Dinv = (double*)(ws + 6039552);   // 262,144
    double* DinvT= (double*)(ws + 6301696);   // 262,144 (end 6,563,840)
    // at arrays live in LT's space (LT unused until chol; gram consumes at first)
    float*  atT  = (float*)(ws + 2097152);           // 24,576
    float*  atO  = (float*)(ws + 2097152 + 24576);   // 49,152

    hipMemsetAsync(flags, 0, 192, stream);

    self_kernel<<<M + N + 1, 64, 0, stream>>>(X_test, A_test, X_obs, A_obs,
                                              s1v, s2v, atT, atO, Bc);

    gram_kernel<<<dim3(32, 64, 3), 128, 0, stream>>>(X_test, atT, s1v,
                                                     X_obs, atO, s2v,
                                                     rho_p, nu_p, g_p,
                                                     Kox, Kxx, Koo, Bc);

    chol_kernel<<<120, 256, 0, stream>>>(Koo, LT, Dinv, DinvT, flags);

    solve_kernel<<<257, 64, 0, stream>>>(Koo, LT, Dinv, DinvT, Bc, ys, b_p, out, kbx, Sp);

    cov_kernel<<<dim3(16, 16), 256, 0, stream>>>(Bc, Kox, Kxx, kbx, Sp, out);
}

// Round 5
// 906.239 us; speedup vs baseline: 1.6746x; 1.1171x over previous
//
#include <hip/hip_runtime.h>
#include <cmath>

// Problem constants
#define M 256
#define N 512
#define P 24
#define D 8

// ---------------------------------------------------------------------------
// self terms: s[i] = sum_{u,v} A[i,u]A[i,v] exp(-0.5*||x_u - x_v||^2)
// plus folded weights at[i,u] = A[i,u]*exp(-0.5*||x_iu||^2).
// Block M+N writes the ones-column of Bc.
// ---------------------------------------------------------------------------
__global__ __launch_bounds__(64) void self_kernel(const float* __restrict__ X_test,
                                                  const float* __restrict__ A_test,
                                                  const float* __restrict__ X_obs,
                                                  const float* __restrict__ A_obs,
                                                  float* __restrict__ s1,
                                                  float* __restrict__ s2,
                                                  float* __restrict__ atT,
                                                  float* __restrict__ atO,
                                                  double* __restrict__ Bc) {
    const int bid = blockIdx.x;
    const int lane = threadIdx.x;
    if (bid == M + N) {  // ones column (col 256 of Bc, col-major [257][512])
#pragma unroll
        for (int t = 0; t < 8; ++t) Bc[(size_t)256 * 512 + 64 * t + lane] = 1.0;
        return;
    }
    const float* X; const float* A; float* s; float* at; int i;
    if (bid < M) { X = X_test; A = A_test; s = s1; at = atT; i = bid; }
    else         { X = X_obs;  A = A_obs;  s = s2; at = atO; i = bid - M; }
    const float* Xi = X + (size_t)i * P * D;
    const float* Ai = A + (size_t)i * P;
    float acc = 0.f;
#pragma unroll
    for (int t = 0; t < 9; ++t) {
        int idx = lane + 64 * t;          // 0..575
        int u = idx / 24;
        int v = idx - u * 24;
        const float* xu = Xi + u * D;
        const float* xv = Xi + v * D;
        float d2 = 0.f;
#pragma unroll
        for (int d = 0; d < D; ++d) { float df = xu[d] - xv[d]; d2 = fmaf(df, df, d2); }
        acc = fmaf(Ai[u] * Ai[v], __expf(-0.5f * d2), acc);
    }
#pragma unroll
    for (int off = 1; off < 64; off <<= 1) acc += __shfl_xor(acc, off, 64);
    if (lane == 0) s[i] = acc;
    if (lane < 24) {
        const float* xp = Xi + lane * D;
        float q = 0.f;
#pragma unroll
        for (int d = 0; d < D; ++d) q = fmaf(xp[d], xp[d], q);
        at[(size_t)i * P + lane] = Ai[lane] * __expf(-0.5f * q);
    }
}

// ---------------------------------------------------------------------------
// fused gram kernel with norm-folded weights:
//   C_ij = sum_u at1[i,u] sum_v at2[j,v] exp(x1_iu . x2_jv)
//   out = nu * exp(-0.5*max(s1[i]+s2[j]-2*C_ij,0)/rho)
// tile: 16 i x 8 j, 128 threads = 16 il x 8 uc (3 u each).
// z=0: Koo lower f64 (+nu*g diag); z=1: Kox f32 [N][M] + Bc f64; z=2: Kxx sym
// ---------------------------------------------------------------------------
__global__ __launch_bounds__(128) void gram_kernel(
    const float* __restrict__ Xt, const float* __restrict__ atT, const float* __restrict__ s1,
    const float* __restrict__ Xo, const float* __restrict__ atO, const float* __restrict__ s2,
    const float* __restrict__ rho_p, const float* __restrict__ nu_p, const float* __restrict__ g_p,
    float* __restrict__ Kox, float* __restrict__ Kxx, double* __restrict__ Koo,
    double* __restrict__ Bc) {
    const int mode = blockIdx.z;
    const int it = blockIdx.x, jt = blockIdx.y;
    const float *X1, *AT1, *S1, *X2, *AT2, *S2;
    if (mode == 0) {
        if (jt > 2 * it + 1) return;
        X1 = Xo; AT1 = atO; S1 = s2; X2 = Xo; AT2 = atO; S2 = s2;
    } else if (mode == 1) {
        if (jt >= 32) return;
        X1 = Xo; AT1 = atO; S1 = s2; X2 = Xt; AT2 = atT; S2 = s1;
    } else {
        if (it >= 16 || jt >= 32 || jt < 2 * it) return;
        X1 = Xt; AT1 = atT; S1 = s1; X2 = Xt; AT2 = atT; S2 = s1;
    }
    const int i0 = it * 16, j0 = jt * 8;
    const int tid = threadIdx.x;
    const int il = tid >> 3, uc = tid & 7;
    const int i = i0 + il;

    __shared__ __align__(16) float X2s[8 * 192];
    __shared__ float A2s[8 * 24];
    __shared__ float S2s[8];
    {
        const float4* gx = (const float4*)(X2 + (size_t)j0 * 192);
        float4* lx = (float4*)X2s;
        for (int idx = tid; idx < 8 * 48; idx += 128) lx[idx] = gx[idx];
        for (int idx = tid; idx < 8 * 24; idx += 128) A2s[idx] = AT2[(size_t)j0 * 24 + idx];
        if (tid < 8) S2s[tid] = S2[j0 + tid];
    }
    __syncthreads();

    float x1r[3][8], at1r[3];
#pragma unroll
    for (int ss = 0; ss < 3; ++ss) {
        const float* p = X1 + ((size_t)i * P + uc * 3 + ss) * D;
#pragma unroll
        for (int d = 0; d < D; ++d) x1r[ss][d] = p[d];
        at1r[ss] = AT1[(size_t)i * P + uc * 3 + ss];
    }
    const float s1i = S1[i];
    const float rho = rho_p[0], nu = nu_p[0], g = g_p[0];

    for (int jj = 0; jj < 8; ++jj) {
        const float* xb = X2s + jj * 192;
        float e0 = 0.f, e1 = 0.f, e2 = 0.f;
#pragma unroll 4
        for (int v = 0; v < 24; ++v) {
            const float4 q0 = ((const float4*)(xb + v * 8))[0];
            const float4 q1 = ((const float4*)(xb + v * 8))[1];
            float x2r[8];
            x2r[0] = q0.x; x2r[1] = q0.y; x2r[2] = q0.z; x2r[3] = q0.w;
            x2r[4] = q1.x; x2r[5] = q1.y; x2r[6] = q1.z; x2r[7] = q1.w;
            const float w2 = A2s[jj * 24 + v];
            float d0 = 0.f, d1 = 0.f, d2 = 0.f;
#pragma unroll
            for (int dd = 0; dd < 8; ++dd) {
                d0 = fmaf(x1r[0][dd], x2r[dd], d0);
                d1 = fmaf(x1r[1][dd], x2r[dd], d1);
                d2 = fmaf(x1r[2][dd], x2r[dd], d2);
            }
            e0 = fmaf(w2, __expf(d0), e0);
            e1 = fmaf(w2, __expf(d1), e1);
            e2 = fmaf(w2, __expf(d2), e2);
        }
        float acc = at1r[0] * e0;
        acc = fmaf(at1r[1], e1, acc);
        acc = fmaf(at1r[2], e2, acc);
        acc += __shfl_xor(acc, 1, 8);
        acc += __shfl_xor(acc, 2, 8);
        acc += __shfl_xor(acc, 4, 8);
        if (uc == 0) {
            const int j = j0 + jj;
            float d2p = fmaxf(s1i + S2s[jj] - 2.f * acc, 0.f);
            float kv = __expf(-0.5f * d2p / rho);
            if (mode == 0) {
                if (j <= i) Koo[(size_t)i * 512 + j] = (double)(nu * (kv + ((i == j) ? g : 0.f)));
            } else if (mode == 1) {
                float val = nu * kv;
                Kox[(size_t)i * 256 + j] = val;
                Bc[(size_t)j * 512 + i] = (double)val;
            } else {
                float val = nu * kv;
                if (j >= i) {
                    Kxx[(size_t)i * 256 + j] = val;
                    if (j > i) Kxx[(size_t)j * 256 + i] = val;
                }
            }
        }
    }
}

// ---------------------------------------------------------------------------
// Whole blocked Cholesky (panel=64) in ONE dispatch. 120 blocks:
// per panel p: [factor(1)] [trsm(7-p)] [syrk((7-p)(8-p)/2)], synchronized by
// device-scope acquire/release counters (zeroed by memsetAsync each launch).
// SPIN FIX (r5): relaxed spin + ONE acquire fence on exit. An acquire load in
// the spin loop emits an L1/L2 invalidate per iteration -> chip-wide L2
// invalidate storm from waiting blocks (r4: 798us @ 0.16% VALU).
// ---------------------------------------------------------------------------
#define NT_(p) (7 - (p))
#define NS_(p) ((7 - (p)) * (8 - (p)) / 2)

__device__ __forceinline__ void spin_ge(int* f, int target) {
    if (threadIdx.x == 0) {
        while (__hip_atomic_load(f, __ATOMIC_RELAXED, __HIP_MEMORY_SCOPE_AGENT) < target)
            __builtin_amdgcn_s_sleep(8);
        __builtin_amdgcn_fence(__ATOMIC_ACQUIRE, "agent");
    }
    __syncthreads();
}

__global__ __launch_bounds__(256) void chol_kernel(double* __restrict__ A,
                                                   double* __restrict__ LT,
                                                   double* __restrict__ Dinv,
                                                   double* __restrict__ DinvT,
                                                   int* __restrict__ flags) {
    int* fdone = flags;        // [8] factor done
    int* tdone = flags + 8;    // [8] trsm count
    int* s00   = flags + 16;   // [8] syrk tile (0,0) done
    int* scol0 = flags + 24;   // [8] syrk col-0 count
    int* sall  = flags + 32;   // [8] syrk total count

    int bid = blockIdx.x, p = 0, rem = bid;
    for (;; ++p) {
        int tot = 1 + NT_(p) + NS_(p);
        if (rem < tot) break;
        rem -= tot;
    }
    const int k0 = p * 64;
    const int tid = threadIdx.x;

    __shared__ double smem[2 * 64 * 65 + 3 * 16 * 17];   // 73 KB

    if (rem == 0) {
        // ---------------- factor block ----------------
        double (*sA)[65] = (double(*)[65])smem;
        double (*sX)[65] = (double(*)[65])(smem + 64 * 65);
        double* sW = smem + 2 * 64 * 65;                 // [3][16][17]
        if (p > 0) spin_ge(&s00[p - 1], 1);
        for (int idx = tid; idx < 4096; idx += 256) {
            int r = idx >> 6, c = idx & 63;
            sA[r][c] = (c <= r) ? A[(size_t)(k0 + r) * 512 + k0 + c] : 0.0;
            sX[r][c] = 0.0;
        }
        __syncthreads();
        for (int q = 0; q < 4; ++q) {
            const int b0 = 16 * q;
            if (tid < 64) {
                // LDL deferred-scale sweep, in-order same-wave LDS
                for (int k = 0; k < 15; ++k) {
                    double inv = 1.0 / sA[b0 + k][b0 + k];
#pragma unroll
                    for (int t = 0; t < 4; ++t) {
                        int idx = tid + 64 * t, r = idx >> 4, c = idx & 15;
                        if (r > k && c > k && c <= r)
                            sA[b0 + r][b0 + c] -= sA[b0 + r][b0 + k] * sA[b0 + c][b0 + k] * inv;
                    }
                    asm volatile("" ::: "memory");
                }
                // scale to true L: read diag first, broadcast via shfl
                double dq = (tid < 16) ? sqrt(sA[b0 + tid][b0 + tid]) : 1.0;
                asm volatile("" ::: "memory");
#pragma unroll
                for (int t = 0; t < 4; ++t) {
                    int idx = tid + 64 * t, r = idx >> 4, c = idx & 15;
                    double dcol = __shfl(dq, c, 64);
                    if (c <= r) sA[b0 + r][b0 + c] = (r == c) ? dcol : sA[b0 + r][b0 + c] / dcol;
                }
                asm volatile("" ::: "memory");
                // X_qq = inv(L_qq): 4 lanes per column
                int c = tid >> 2, qd = tid & 3;
                if (qd == 0) sX[b0 + c][b0 + c] = 1.0 / sA[b0 + c][b0 + c];
                asm volatile("" ::: "memory");
                for (int r = 1; r < 16; ++r) {
                    double partial = 0.0;
                    for (int t = c + qd; t < r; t += 4)
                        partial = fma(sA[b0 + r][b0 + t], sX[b0 + t][b0 + c], partial);
                    partial += __shfl_xor(partial, 1, 4);
                    partial += __shfl_xor(partial, 2, 4);
                    if (qd == 0 && r > c)
                        sX[b0 + r][b0 + c] = -partial / sA[b0 + r][b0 + r];
                    asm volatile("" ::: "memory");
                }
            }
            __syncthreads();
            if (q < 3) {
                const int nrows = 48 - b0;
                const int cells = nrows * 16;
                double tv[3];
#pragma unroll
                for (int ii = 0; ii < 3; ++ii) {
                    int idx = tid + 256 * ii;
                    tv[ii] = 0.0;
                    if (idx < cells) {
                        int a = b0 + 16 + (idx >> 4), cc = idx & 15;
                        double acc = 0.0;
                        for (int t = 0; t <= cc; ++t)
                            acc = fma(sA[a][b0 + t], sX[b0 + cc][b0 + t], acc);
                        tv[ii] = acc;
                    }
                }
                __syncthreads();
#pragma unroll
                for (int ii = 0; ii < 3; ++ii) {
                    int idx = tid + 256 * ii;
                    if (idx < cells) {
                        int a = b0 + 16 + (idx >> 4), cc = idx & 15;
                        sA[a][b0 + cc] = tv[ii];
                    }
                }
                __syncthreads();
                for (int idx = tid; idx < nrows * nrows; idx += 256) {
                    int r = b0 + 16 + idx / nrows, cc = b0 + 16 + idx % nrows;
                    if (cc <= r) {
                        double acc = 0.0;
#pragma unroll
                        for (int t = 0; t < 16; ++t)
                            acc = fma(sA[r][b0 + t], sA[cc][b0 + t], acc);
                        sA[r][cc] -= acc;
                    }
                }
                __syncthreads();
            }
        }
        // assemble off-diagonal 16x16 blocks of X = inv(L64): 3 levels
        for (int d = 1; d <= 3; ++d) {
            __syncthreads();
            int npairs = 4 - d;
            for (int i2 = tid; i2 < npairs * 256; i2 += 256) {
                int pr = i2 >> 8, cell = i2 & 255, r = cell >> 4, c = cell & 15;
                int qc = pr, qr = pr + d;
                double w = 0.0;
                for (int t = 16 * qc; t < 16 * qr; ++t)
                    w = fma(sA[16 * qr + r][t], sX[t][16 * qc + c], w);
                sW[pr * 272 + r * 17 + c] = w;
            }
            __syncthreads();
            for (int i2 = tid; i2 < npairs * 256; i2 += 256) {
                int pr = i2 >> 8, cell = i2 & 255, r = cell >> 4, c = cell & 15;
                int qc = pr, qr = pr + d;
                double x = 0.0;
                for (int t = 0; t <= r; ++t)
                    x = fma(sX[16 * qr + r][16 * qr + t], sW[pr * 272 + t * 17 + c], x);
                sX[16 * qr + r][16 * qc + c] = -x;
            }
        }
        __syncthreads();
        for (int idx = tid; idx < 4096; idx += 256) {
            int r = idx >> 6, c = idx & 63;
            if (c <= r) {
                double lv = sA[r][c];
                A[(size_t)(k0 + r) * 512 + k0 + c] = lv;
                LT[(size_t)(k0 + c) * 512 + k0 + r] = lv;
            }
            double xv = sX[r][c];
            Dinv[(size_t)p * 4096 + idx] = xv;
            DinvT[(size_t)p * 4096 + (size_t)c * 64 + r] = xv;
        }
        __syncthreads();
        if (tid == 0) __hip_atomic_fetch_add(&fdone[p], 1, __ATOMIC_RELEASE, __HIP_MEMORY_SCOPE_AGENT);

    } else if (rem <= NT_(p)) {
        // ---------------- trsm block: L21 = A21 * Dinv^T ----------------
        double (*sA)[65] = (double(*)[65])smem;
        double (*sB)[65] = (double(*)[65])(smem + 64 * 65);
        const int b = rem - 1;
        const int i0 = k0 + 64 + b * 64;
        if (p > 0) spin_ge(&scol0[p - 1], NT_(p - 1));
        spin_ge(&fdone[p], 1);
        for (int idx = tid; idx < 4096; idx += 256) {
            int r = idx >> 6, c = idx & 63;
            sA[r][c] = A[(size_t)(i0 + r) * 512 + k0 + c];
            sB[r][c] = DinvT[(size_t)p * 4096 + idx];
        }
        __syncthreads();
        const int tx = tid & 15, ty = tid >> 4;
        double acc[4][4] = {};
        for (int t = 0; t < 64; ++t) {
            double a0 = sA[4 * ty + 0][t], a1 = sA[4 * ty + 1][t];
            double a2 = sA[4 * ty + 2][t], a3 = sA[4 * ty + 3][t];
            double b0 = sB[t][4 * tx + 0], b1 = sB[t][4 * tx + 1];
            double b2 = sB[t][4 * tx + 2], b3 = sB[t][4 * tx + 3];
            acc[0][0] = fma(a0, b0, acc[0][0]); acc[0][1] = fma(a0, b1, acc[0][1]);
            acc[0][2] = fma(a0, b2, acc[0][2]); acc[0][3] = fma(a0, b3, acc[0][3]);
            acc[1][0] = fma(a1, b0, acc[1][0]); acc[1][1] = fma(a1, b1, acc[1][1]);
            acc[1][2] = fma(a1, b2, acc[1][2]); acc[1][3] = fma(a1, b3, acc[1][3]);
            acc[2][0] = fma(a2, b0, acc[2][0]); acc[2][1] = fma(a2, b1, acc[2][1]);
            acc[2][2] = fma(a2, b2, acc[2][2]); acc[2][3] = fma(a2, b3, acc[2][3]);
            acc[3][0] = fma(a3, b0, acc[3][0]); acc[3][1] = fma(a3, b1, acc[3][1]);
            acc[3][2] = fma(a3, b2, acc[3][2]); acc[3][3] = fma(a3, b3, acc[3][3]);
        }
#pragma unroll
        for (int r = 0; r < 4; ++r)
#pragma unroll
            for (int c = 0; c < 4; ++c) {
                A[(size_t)(i0 + 4 * ty + r) * 512 + k0 + 4 * tx + c] = acc[r][c];
                LT[(size_t)(k0 + 4 * tx + c) * 512 + i0 + 4 * ty + r] = acc[r][c];
            }
        __syncthreads();
        if (tid == 0) __hip_atomic_fetch_add(&tdone[p], 1, __ATOMIC_RELEASE, __HIP_MEMORY_SCOPE_AGENT);

    } else {
        // ---------------- syrk block: A[i0,j0] -= Li * Lj^T ----------------
        double (*Li)[65] = (double(*)[65])smem;
        double (*Lj)[65] = (double(*)[65])(smem + 64 * 65);
        int s = rem - 1 - NT_(p);
        int bi = 0;
        while (s >= (bi + 1) * (bi + 2) / 2) ++bi;
        int bj = s - bi * (bi + 1) / 2;
        const int i0 = k0 + 64 + bi * 64, j0 = k0 + 64 + bj * 64;
        if (p > 0) spin_ge(&sall[p - 1], NS_(p - 1));
        spin_ge(&tdone[p], NT_(p));
        for (int idx = tid; idx < 4096; idx += 256) {
            int r = idx >> 6, c = idx & 63;
            Li[r][c] = A[(size_t)(i0 + r) * 512 + k0 + c];
            Lj[r][c] = A[(size_t)(j0 + r) * 512 + k0 + c];
        }
        __syncthreads();
        const int tx = tid & 15, ty = tid >> 4;
        double acc[4][4] = {};
        for (int t = 0; t < 64; ++t) {
            double a0 = Li[4 * ty + 0][t], a1 = Li[4 * ty + 1][t];
            double a2 = Li[4 * ty + 2][t], a3 = Li[4 * ty + 3][t];
            double b0 = Lj[4 * tx + 0][t], b1 = Lj[4 * tx + 1][t];
            double b2 = Lj[4 * tx + 2][t], b3 = Lj[4 * tx + 3][t];
            acc[0][0] = fma(a0, b0, acc[0][0]); acc[0][1] = fma(a0, b1, acc[0][1]);
            acc[0][2] = fma(a0, b2, acc[0][2]); acc[0][3] = fma(a0, b3, acc[0][3]);
            acc[1][0] = fma(a1, b0, acc[1][0]); acc[1][1] = fma(a1, b1, acc[1][1]);
            acc[1][2] = fma(a1, b2, acc[1][2]); acc[1][3] = fma(a1, b3, acc[1][3]);
            acc[2][0] = fma(a2, b0, acc[2][0]); acc[2][1] = fma(a2, b1, acc[2][1]);
            acc[2][2] = fma(a2, b2, acc[2][2]); acc[2][3] = fma(a2, b3, acc[2][3]);
            acc[3][0] = fma(a3, b0, acc[3][0]); acc[3][1] = fma(a3, b1, acc[3][1]);
            acc[3][2] = fma(a3, b2, acc[3][2]); acc[3][3] = fma(a3, b3, acc[3][3]);
        }
#pragma unroll
        for (int r = 0; r < 4; ++r)
#pragma unroll
            for (int c = 0; c < 4; ++c) {
                int gi = i0 + 4 * ty + r, gj = j0 + 4 * tx + c;
                if (bi != bj || gj <= gi) A[(size_t)gi * 512 + gj] -= acc[r][c];
            }
        __syncthreads();
        if (tid == 0) {
            __hip_atomic_fetch_add(&sall[p], 1, __ATOMIC_RELEASE, __HIP_MEMORY_SCOPE_AGENT);
            if (bj == 0) __hip_atomic_fetch_add(&scol0[p], 1, __ATOMIC_RELEASE, __HIP_MEMORY_SCOPE_AGENT);
            if (bi == 0 && bj == 0) __hip_atomic_fetch_add(&s00[p], 1, __ATOMIC_RELEASE, __HIP_MEMORY_SCOPE_AGENT);
        }
    }
}

// ---------------------------------------------------------------------------
// fused solve per column: L y = b (fwd), L^T z = y (bwd), then column
// reductions: mean/kbx/S. One 64-lane block per RHS column.
// ---------------------------------------------------------------------------
__global__ __launch_bounds__(64) void solve_kernel(const double* __restrict__ L,
                                                   const double* __restrict__ U,
                                                   const double* __restrict__ Dinv,
                                                   const double* __restrict__ DinvT,
                                                   double* __restrict__ B,
                                                   const float* __restrict__ ys,
                                                   const float* __restrict__ b_p,
                                                   float* __restrict__ out,
                                                   double* __restrict__ kbx,
                                                   double* __restrict__ Sp) {
    const int c = blockIdx.x, lane = threadIdx.x;
    double* col = B + (size_t)c * 512;
    __shared__ double y[512];
    __shared__ double z[512];
    __shared__ double v[64];
    double breg[8];
#pragma unroll
    for (int k = 0; k < 8; ++k) breg[k] = col[64 * k + lane];
    // forward: per panel, v = b - L21*y_prev ; y_panel = Dinv * v
    for (int k = 0; k < 8; ++k) {
        const double* row = L + (size_t)(64 * k + lane) * 512;
        double acc = 0.0;
        for (int j = 0; j < 64 * k; j += 8) {
            double2 l0 = *(const double2*)(row + j + 0);
            double2 l1 = *(const double2*)(row + j + 2);
            double2 l2 = *(const double2*)(row + j + 4);
            double2 l3 = *(const double2*)(row + j + 6);
            acc = fma(l0.x, y[j + 0], acc); acc = fma(l0.y, y[j + 1], acc);
            acc = fma(l1.x, y[j + 2], acc); acc = fma(l1.y, y[j + 3], acc);
            acc = fma(l2.x, y[j + 4], acc); acc = fma(l2.y, y[j + 5], acc);
            acc = fma(l3.x, y[j + 6], acc); acc = fma(l3.y, y[j + 7], acc);
        }
        v[lane] = breg[k] - acc;
        __syncthreads();
        const double* Dk = DinvT + (size_t)k * 4096;
        double yr = 0.0;
#pragma unroll 8
        for (int t = 0; t < 64; ++t) yr = fma(Dk[t * 64 + lane], v[t], yr);
        y[64 * k + lane] = yr;
        __syncthreads();
    }
    // backward with U = L^T
    for (int k = 7; k >= 0; --k) {
        const double* row = U + (size_t)(64 * k + lane) * 512;
        double acc = 0.0;
        for (int j = 64 * (k + 1); j < 512; j += 8) {
            double2 l0 = *(const double2*)(row + j + 0);
            double2 l1 = *(const double2*)(row + j + 2);
            double2 l2 = *(const double2*)(row + j + 4);
            double2 l3 = *(const double2*)(row + j + 6);
            acc = fma(l0.x, z[j + 0], acc); acc = fma(l0.y, z[j + 1], acc);
            acc = fma(l1.x, z[j + 2], acc); acc = fma(l1.y, z[j + 3], acc);
            acc = fma(l2.x, z[j + 4], acc); acc = fma(l2.y, z[j + 5], acc);
            acc = fma(l3.x, z[j + 6], acc); acc = fma(l3.y, z[j + 7], acc);
        }
        v[lane] = y[64 * k + lane] - acc;
        __syncthreads();
        const double* Dk = Dinv + (size_t)k * 4096;
        double zr = 0.0;
#pragma unroll 8
        for (int t = 0; t < 64; ++t) zr = fma(Dk[t * 64 + lane], v[t], zr);
        z[64 * k + lane] = zr;
        __syncthreads();
    }
    // write back + column reductions
    const double b = (double)b_p[0];
    double s0 = 0.0, s1 = 0.0;
#pragma unroll
    for (int k = 0; k < 8; ++k) {
        int n = 64 * k + lane;
        double zv = z[n];
        col[n] = zv;
        s0 += zv;
        s1 = fma(zv, (double)ys[n] - b, s1);
    }
#pragma unroll
    for (int off = 1; off < 64; off <<= 1) {
        s0 += __shfl_xor(s0, off, 64);
        s1 += __shfl_xor(s1, off, 64);
    }
    if (lane == 0) {
        if (c < 256) { out[c] = (float)(b + s1); kbx[c] = s0; }
        else Sp[0] = s0;
    }
}

// cov[i][j] = Kxx[i][j] - sum_n Z[i][n]*Kox[n][j] + (1-kbx[i])(1-kbx[j])/S
__global__ __launch_bounds__(256) void cov_kernel(const double* __restrict__ Z,
                                                  const float* __restrict__ Kox,
                                                  const float* __restrict__ Kxx,
                                                  const double* __restrict__ kbx,
                                                  const double* __restrict__ Sp,
                                                  float* __restrict__ out) {
    const int bj = blockIdx.x, bi = blockIdx.y;
    const int tx = threadIdx.x & 15, ty = threadIdx.x >> 4;
    const int i = bi * 16 + ty, j = bj * 16 + tx;
    __shared__ double sZ[16][17];
    __shared__ float sK[16][17];
    double acc = 0.0;
    for (int kt = 0; kt < 32; ++kt) {
        sZ[ty][tx] = Z[(size_t)i * 512 + kt * 16 + tx];
        sK[ty][tx] = Kox[(size_t)(kt * 16 + ty) * 256 + j];
        __syncthreads();
#pragma unroll
        for (int t = 0; t < 16; ++t) acc = fma(sZ[ty][t], (double)sK[t][tx], acc);
        __syncthreads();
    }
    const double S = Sp[0];
    const double corr = (1.0 - kbx[i]) * (1.0 - kbx[j]) / S;
    out[(size_t)(1 + i) * 256 + j] = (float)((double)Kxx[(size_t)i * 256 + j] - acc + corr);
}

// ---------------------------------------------------------------------------
extern "C" void kernel_launch(void* const* d_in, const int* in_sizes, int n_in,
                              void* d_out, int out_size, void* d_ws, size_t ws_size,
                              hipStream_t stream) {
    const float* X_test = (const float*)d_in[0];
    const float* A_test = (const float*)d_in[1];
    const float* X_obs  = (const float*)d_in[2];
    const float* A_obs  = (const float*)d_in[3];
    const float* ys     = (const float*)d_in[4];
    const float* rho_p  = (const float*)d_in[5];
    const float* g_p    = (const float*)d_in[6];
    const float* nu_p   = (const float*)d_in[7];
    const float* b_p    = (const float*)d_in[8];
    float* out = (float*)d_out;
    char* ws = (char*)d_ws;

    double* Koo  = (double*)(ws + 0);         // 2,097,152
    double* LT   = (double*)(ws + 2097152);   // 2,097,152
    double* Bc   = (double*)(ws + 4194304);   // 1,052,672
    float*  Kox  = (float*) (ws + 5246976);   // 524,288
    float*  Kxx  = (float*) (ws + 5771264);   // 262,144
    float*  s1v  = (float*) (ws + 6033408);   // 1,024
    float*  s2v  = (float*) (ws + 6034432);   // 2,048
    double* kbx  = (double*)(ws + 6036480);   // 2,048
    double* Sp   = (double*)(ws + 6038528);   // 8 (+pad)
    int*    flags= (int*)   (ws + 6038784);   // 160 B (inside Sp pad)
    double* Dinv = (double*)(ws + 6039552);   // 262,144
    double* DinvT= (double*)(ws + 6301696);   // 262,144 (end 6,563,840)
    // at arrays live in LT's space (LT unused until chol; gram consumes at first)
    float*  atT  = (float*)(ws + 2097152);           // 24,576
    float*  atO  = (float*)(ws + 2097152 + 24576);   // 49,152

    hipMemsetAsync(flags, 0, 192, stream);

    self_kernel<<<M + N + 1, 64, 0, stream>>>(X_test, A_test, X_obs, A_obs,
                                              s1v, s2v, atT, atO, Bc);

    gram_kernel<<<dim3(32, 64, 3), 128, 0, stream>>>(X_test, atT, s1v,
                                                     X_obs, atO, s2v,
                                                     rho_p, nu_p, g_p,
                                                     Kox, Kxx, Koo, Bc);

    chol_kernel<<<120, 256, 0, stream>>>(Koo, LT, Dinv, DinvT, flags);

    solve_kernel<<<257, 64, 0, stream>>>(Koo, LT, Dinv, DinvT, Bc, ys, b_p, out, kbx, Sp);

    cov_kernel<<<dim3(16, 16), 256, 0, stream>>>(Bc, Kox, Kxx, kbx, Sp, out);
}